// Round 5
// baseline (558.415 us; speedup 1.0000x reference)
//
#include <hip/hip_runtime.h>
#include <hip/hip_bf16.h>
#include <stdint.h>

#define T_LEN   2048
#define BATCH   4
#define DMODEL  1024
#define DINNER  2048
#define DSTATE  16
#define DTRANK  64
#define MROWS   (BATCH*T_LEN)   // 8192
#define NCHUNK  16
#define CLEN    (T_LEN / NCHUNK)  // 128

typedef __bf16 bf16x8_t __attribute__((ext_vector_type(8)));
typedef float  f32x4_t  __attribute__((ext_vector_type(4)));

__device__ __forceinline__ uint16_t f2b(float f) {
    uint32_t u = __float_as_uint(f);
    u += 0x7fffu + ((u >> 16) & 1u);          // round-to-nearest-even
    return (uint16_t)(u >> 16);
}
__device__ __forceinline__ float b2f(uint16_t h) {
    return __uint_as_float(((uint32_t)h) << 16);
}

// async global->LDS, 16B per lane (m97 recipe: LDS dest must be
// wave-uniform base + lane*16, which As[tid*8] satisfies)
__device__ __forceinline__ void gload16(const void* g, void* l) {
    __builtin_amdgcn_global_load_lds(
        (const __attribute__((address_space(1))) void*)g,
        (__attribute__((address_space(3))) void*)l, 16, 0, 0);
}

// ---------------------------------------------------------------------------
// x (t,b,c) fp32  ->  xb16 (b*T+t, c) bf16   (permute + convert)
// ---------------------------------------------------------------------------
__global__ __launch_bounds__(256) void convert_x_kernel(
    const float* __restrict__ x, uint16_t* __restrict__ xb)
{
    int tb = blockIdx.x;            // 0..8191, = t*4 + b
    int t = tb >> 2, b = tb & 3;
    int c = threadIdx.x * 4;
    const float4 v = *(const float4*)(x + ((size_t)tb) * DMODEL + c);
    uint16_t* dst = xb + ((size_t)(b * T_LEN + t)) * DMODEL + c;
    uint2 p;
    p.x = (uint32_t)f2b(v.x) | ((uint32_t)f2b(v.y) << 16);
    p.y = (uint32_t)f2b(v.z) | ((uint32_t)f2b(v.w) << 16);
    *(uint2*)dst = p;
}

// ---------------------------------------------------------------------------
// transpose + convert: src fp32 [R][C] -> dst bf16 [Cpad][R], zero-fill c>=C
// ---------------------------------------------------------------------------
__global__ __launch_bounds__(256) void transpose_cvt_kernel(
    const float* __restrict__ src, uint16_t* __restrict__ dst,
    int R, int C, int Cpad)
{
    __shared__ float tile[32][33];
    int r0 = blockIdx.x * 32;
    int c0 = blockIdx.y * 32;
    int tx = threadIdx.x, ty = threadIdx.y;
#pragma unroll
    for (int i = 0; i < 32; i += 8) {
        int r = r0 + ty + i, c = c0 + tx;
        tile[ty + i][tx] = (r < R && c < C) ? src[(size_t)r * C + c] : 0.f;
    }
    __syncthreads();
#pragma unroll
    for (int i = 0; i < 32; i += 8) {
        int dr = c0 + ty + i;   // dst row = src col
        int dc = r0 + tx;       // dst col = src row
        if (dr < Cpad && dc < R) dst[(size_t)dr * R + dc] = f2b(tile[tx][ty + i]);
    }
}

// ---------------------------------------------------------------------------
// Generic bf16 MFMA GEMM: C[M][N] = A[M][K] * Bt[N][K]^T
// global_load_lds width-16 staging (m97 structure)
// ---------------------------------------------------------------------------
#define EPI_BF16  0
#define EPI_F32G  1
#define EPI_SP    2
#define EPI_REMAP 3

template <int EPI, bool SPLITK>
__global__ __launch_bounds__(256) void gemm_bt_kernel(
    const uint16_t* __restrict__ A, const uint16_t* __restrict__ Bt,
    void* __restrict__ CoutBase, const float* __restrict__ bias,
    int N, int K, int ldc, int ksplit)
{
    __shared__ uint16_t As[128 * 32];
    __shared__ uint16_t Bs[128 * 32];

    int tid = threadIdx.x;
    int bm = blockIdx.x * 128, bn = blockIdx.y * 128;
    int kbeg = SPLITK ? blockIdx.z * ksplit : 0;
    int kend = SPLITK ? kbeg + ksplit : K;
    void* Cout = SPLITK
        ? (void*)((float*)CoutBase + (size_t)blockIdx.z * MROWS * ldc)
        : CoutBase;

    const uint16_t* ap0 = A  + (size_t)(bm + (tid >> 2)) * K + kbeg + (tid & 3) * 8;
    const uint16_t* ap1 = ap0 + (size_t)64 * K;
    const uint16_t* bp0 = Bt + (size_t)(bn + (tid >> 2)) * K + kbeg + (tid & 3) * 8;
    const uint16_t* bp1 = bp0 + (size_t)64 * K;

    f32x4_t acc[4][4];
#pragma unroll
    for (int i = 0; i < 4; i++)
#pragma unroll
        for (int j = 0; j < 4; j++) acc[i][j] = (f32x4_t){0.f, 0.f, 0.f, 0.f};

    int wid = tid >> 6, lane = tid & 63;
    int wm = (wid & 1) * 64, wn = (wid >> 1) * 64;
    int lr = lane & 15, lq = lane >> 4;
    const uint16_t* Afrag = &As[(wm + lr) * 32 + lq * 8];
    const uint16_t* Bfrag = &Bs[(wn + lr) * 32 + lq * 8];

    for (int k0 = kbeg; k0 < kend; k0 += 32) {
        __syncthreads();                       // LDS safe to overwrite
        gload16(ap0, &As[(size_t)tid * 8]);
        gload16(ap1, &As[(size_t)(tid + 256) * 8]);
        gload16(bp0, &Bs[(size_t)tid * 8]);
        gload16(bp1, &Bs[(size_t)(tid + 256) * 8]);
        ap0 += 32; ap1 += 32; bp0 += 32; bp1 += 32;
        __syncthreads();                       // drains vmcnt (async LDS stores)

        bf16x8_t av[4], bv[4];
#pragma unroll
        for (int i = 0; i < 4; i++) av[i] = *(const bf16x8_t*)(Afrag + i * 512);
#pragma unroll
        for (int j = 0; j < 4; j++) bv[j] = *(const bf16x8_t*)(Bfrag + j * 512);
#pragma unroll
        for (int i = 0; i < 4; i++)
#pragma unroll
            for (int j = 0; j < 4; j++)
                acc[i][j] = __builtin_amdgcn_mfma_f32_16x16x32_bf16(
                    av[i], bv[j], acc[i][j], 0, 0, 0);
    }

#pragma unroll
    for (int i = 0; i < 4; i++) {
#pragma unroll
        for (int j = 0; j < 4; j++) {
            int col = bn + wn + j * 16 + lr;
#pragma unroll
            for (int r = 0; r < 4; r++) {
                int row = bm + wm + i * 16 + lq * 4 + r;
                float v = acc[i][j][r];
                if (EPI == EPI_BF16) {
                    ((uint16_t*)Cout)[(size_t)row * ldc + col] = f2b(v);
                } else if (EPI == EPI_F32G) {
                    if (col < N) ((float*)Cout)[(size_t)row * ldc + col] = v;
                } else if (EPI == EPI_SP) {
                    float xv = v + bias[col];
                    float sp = (xv > 15.f) ? xv : __logf(1.f + __expf(xv));
                    ((uint16_t*)Cout)[(size_t)row * ldc + col] = f2b(sp);
                } else {
                    int bb = row >> 11, tt = row & (T_LEN - 1);
                    ((float*)Cout)[((size_t)(tt * BATCH + bb)) * ldc + col] = v;
                }
            }
        }
    }
}

// ---------------------------------------------------------------------------
// depthwise causal conv (width 4) + bias + SiLU — register sliding window.
// ---------------------------------------------------------------------------
#define CROWS 16

__global__ __launch_bounds__(256) void conv_silu_kernel(
    const uint16_t* __restrict__ z, const float* __restrict__ cw,
    const float* __restrict__ cb, uint16_t* __restrict__ u)
{
    int c0 = threadIdx.x * 8;           // 0..2040
    int m0 = blockIdx.x * CROWS;

    float w[8][4], bias[8];
#pragma unroll
    for (int c = 0; c < 8; ++c)
        *(float4*)w[c] = *(const float4*)(cw + (size_t)(c0 + c) * 4);
    *(float4*)&bias[0] = *(const float4*)(cb + c0);
    *(float4*)&bias[4] = *(const float4*)(cb + c0 + 4);

    float fw[4][8];
    bool seqstart = (m0 & (T_LEN - 1)) == 0;
#pragma unroll
    for (int j = 0; j < 3; ++j) {
        int m = m0 - 3 + j;
        if (seqstart) {
#pragma unroll
            for (int c = 0; c < 8; ++c) fw[j + 1][c] = 0.f;
        } else {
            uint4 v = *(const uint4*)(z + (size_t)m * 4096 + c0);
            fw[j + 1][0] = b2f((uint16_t)(v.x & 0xffff)); fw[j + 1][1] = b2f((uint16_t)(v.x >> 16));
            fw[j + 1][2] = b2f((uint16_t)(v.y & 0xffff)); fw[j + 1][3] = b2f((uint16_t)(v.y >> 16));
            fw[j + 1][4] = b2f((uint16_t)(v.z & 0xffff)); fw[j + 1][5] = b2f((uint16_t)(v.z >> 16));
            fw[j + 1][6] = b2f((uint16_t)(v.w & 0xffff)); fw[j + 1][7] = b2f((uint16_t)(v.w >> 16));
        }
    }

#pragma unroll
    for (int t = 0; t < CROWS; ++t) {
        int m = m0 + t;
        int s = t & 3;
        uint4 v = *(const uint4*)(z + (size_t)m * 4096 + c0);
        fw[s][0] = b2f((uint16_t)(v.x & 0xffff)); fw[s][1] = b2f((uint16_t)(v.x >> 16));
        fw[s][2] = b2f((uint16_t)(v.y & 0xffff)); fw[s][3] = b2f((uint16_t)(v.y >> 16));
        fw[s][4] = b2f((uint16_t)(v.z & 0xffff)); fw[s][5] = b2f((uint16_t)(v.z >> 16));
        fw[s][6] = b2f((uint16_t)(v.w & 0xffff)); fw[s][7] = b2f((uint16_t)(v.w >> 16));
        uint16_t out[8];
#pragma unroll
        for (int c = 0; c < 8; ++c) {
            float a = bias[c];
#pragma unroll
            for (int j = 0; j < 4; ++j)
                a = fmaf(fw[(t + 1 + j) & 3][c], w[c][j], a);
            float sv = a / (1.f + __expf(-a));
            out[c] = f2b(sv);
        }
        uint4 o;
        o.x = (uint32_t)out[0] | ((uint32_t)out[1] << 16);
        o.y = (uint32_t)out[2] | ((uint32_t)out[3] << 16);
        o.z = (uint32_t)out[4] | ((uint32_t)out[5] << 16);
        o.w = (uint32_t)out[6] | ((uint32_t)out[7] << 16);
        *(uint4*)(u + (size_t)m * DINNER + c0) = o;
    }
}

// ---------------------------------------------------------------------------
// reduce split-K partials of x_proj: xdbl = sum_z xpart[z], dr16 = bf16(cols<64)
// ---------------------------------------------------------------------------
__global__ __launch_bounds__(128) void reduce_xdbl_kernel(
    const float* __restrict__ xpart, float* __restrict__ xdbl,
    uint16_t* __restrict__ dr16)
{
    int m = blockIdx.x, r = threadIdx.x;
    if (r >= 96) return;
    const size_t stride = (size_t)MROWS * 96;
    size_t idx = (size_t)m * 96 + r;
    float s = xpart[idx] + xpart[stride + idx]
            + xpart[2 * stride + idx] + xpart[3 * stride + idx];
    xdbl[idx] = s;
    if (r < DTRANK) dr16[(size_t)m * DTRANK + r] = f2b(s);
}

// ---------------------------------------------------------------------------
// CHUNKED SELECTIVE SCAN, n-split: thread = (b, d, n-half, chunk), 8 states
// in regs. Partner (other n-half) is lane^32 in the same wave, so the final
// y-reduction is ONE __shfl_xor. 2x grid vs R3 (occupancy 20%->40%), half
// the per-thread serial VALU chain.
// ---------------------------------------------------------------------------
#define LOG2E 1.44269504088896340736f

__global__ __launch_bounds__(256) void scan_part1_kernel(
    const uint16_t* __restrict__ delta16, const uint16_t* __restrict__ u16,
    const float* __restrict__ xdbl, const float* __restrict__ A_log,
    float* __restrict__ Pws, float* __restrict__ Qws)
{
    int lane = threadIdx.x & 63;
    int nh   = lane >> 5;                 // n-half: 0 -> n 0..7, 1 -> n 8..15
    int nb   = nh * 8;
    int d = blockIdx.x * 128 + (threadIdx.x >> 6) * 32 + (lane & 31);
    int b = blockIdx.y;
    int c = blockIdx.z;
    float ae[8];
#pragma unroll
    for (int n = 0; n < 8; ++n)
        ae[n] = -__expf(A_log[d * DSTATE + nb + n]) * LOG2E;
    float h[8], P[8];
#pragma unroll
    for (int n = 0; n < 8; ++n) { h[n] = 0.f; P[n] = 1.f; }
    size_t mbase = (size_t)b * T_LEN + (size_t)c * CLEN;

#pragma unroll 4
    for (int t = 0; t < CLEN; ++t) {
        size_t m = mbase + t;
        float delta = b2f(delta16[m * DINNER + d]);
        float du    = delta * b2f(u16[m * DINNER + d]);
        float Bv[8];
        *(float4*)&Bv[0] = *(const float4*)(xdbl + m * 96 + 64 + nb);
        *(float4*)&Bv[4] = *(const float4*)(xdbl + m * 96 + 68 + nb);
#pragma unroll
        for (int n = 0; n < 8; ++n) {
            float w = __builtin_amdgcn_exp2f(delta * ae[n]);
            h[n] = fmaf(w, h[n], du * Bv[n]);
            P[n] *= w;
        }
    }
    size_t base = (((size_t)c * BATCH + b) * DINNER + d) * DSTATE + nb;
    *(float4*)(Pws + base)     = *(float4*)&P[0];
    *(float4*)(Pws + base + 4) = *(float4*)&P[4];
    *(float4*)(Qws + base)     = *(float4*)&h[0];
    *(float4*)(Qws + base + 4) = *(float4*)&h[4];
}

// in-place: H0 for chunk c overwrites Pws[c]
__global__ __launch_bounds__(256) void scan_combine_kernel(
    float* __restrict__ Pws, const float* __restrict__ Qws)
{
    size_t i = (size_t)blockIdx.x * 256 + threadIdx.x;  // BATCH*DINNER*DSTATE
    const size_t stride = (size_t)BATCH * DINNER * DSTATE;
    float h = 0.f;
#pragma unroll
    for (int c = 0; c < NCHUNK; ++c) {
        float P = Pws[c * stride + i];
        float Q = Qws[c * stride + i];
        Pws[c * stride + i] = h;        // chunk-c initial state
        h = fmaf(P, h, Q);
    }
}

__global__ __launch_bounds__(256) void scan_part3_kernel(
    const uint16_t* __restrict__ delta16, const uint16_t* __restrict__ u16,
    const float* __restrict__ xdbl, const uint16_t* __restrict__ z16,
    const float* __restrict__ A_log, const float* __restrict__ Dvec,
    const float* __restrict__ H0ws, uint16_t* __restrict__ y16)
{
    int lane = threadIdx.x & 63;
    int nh   = lane >> 5;
    int nb   = nh * 8;
    int d = blockIdx.x * 128 + (threadIdx.x >> 6) * 32 + (lane & 31);
    int b = blockIdx.y;
    int c = blockIdx.z;
    float ae[8];
#pragma unroll
    for (int n = 0; n < 8; ++n)
        ae[n] = -__expf(A_log[d * DSTATE + nb + n]) * LOG2E;
    float Dd = Dvec[d];
    float h[8];
    size_t hbase = (((size_t)c * BATCH + b) * DINNER + d) * DSTATE + nb;
    *(float4*)&h[0] = *(const float4*)(H0ws + hbase);
    *(float4*)&h[4] = *(const float4*)(H0ws + hbase + 4);
    size_t mbase = (size_t)b * T_LEN + (size_t)c * CLEN;

#pragma unroll 4
    for (int t = 0; t < CLEN; ++t) {
        size_t m = mbase + t;
        float delta = b2f(delta16[m * DINNER + d]);
        float uu    = b2f(u16[m * DINNER + d]);
        float rg    = b2f(z16[m * 4096 + DINNER + d]);
        float du    = delta * uu;
        float Bv[8], Cv[8];
        *(float4*)&Bv[0] = *(const float4*)(xdbl + m * 96 + 64 + nb);
        *(float4*)&Bv[4] = *(const float4*)(xdbl + m * 96 + 68 + nb);
        *(float4*)&Cv[0] = *(const float4*)(xdbl + m * 96 + 80 + nb);
        *(float4*)&Cv[4] = *(const float4*)(xdbl + m * 96 + 84 + nb);
        float p = 0.f;
#pragma unroll
        for (int n = 0; n < 8; ++n) {
            float w = __builtin_amdgcn_exp2f(delta * ae[n]);
            h[n] = fmaf(w, h[n], du * Bv[n]);
            p = fmaf(h[n], Cv[n], p);
        }
        p += __shfl_xor(p, 32);          // add partner half's contribution
        if (nh == 0) {
            float y   = fmaf(uu, Dd, p);
            float sig = 1.f / (1.f + __expf(-rg));
            y16[m * DINNER + d] = f2b(y * rg * sig);
        }
    }
}

// ---------------------------------------------------------------------------
extern "C" void kernel_launch(void* const* d_in, const int* in_sizes, int n_in,
                              void* d_out, int out_size, void* d_ws, size_t ws_size,
                              hipStream_t stream)
{
    const float* x     = (const float*)d_in[0];
    const float* W_in  = (const float*)d_in[1];
    const float* cw    = (const float*)d_in[2];
    const float* cb    = (const float*)d_in[3];
    const float* W_x   = (const float*)d_in[4];
    const float* W_dt  = (const float*)d_in[5];
    const float* b_dt  = (const float*)d_in[6];
    const float* A_log = (const float*)d_in[7];
    const float* Dv    = (const float*)d_in[8];
    const float* W_out = (const float*)d_in[9];

    char* ws = (char*)d_ws;
    size_t off = 0;
    uint16_t* xb16    = (uint16_t*)(ws + off); off += (size_t)MROWS * DMODEL * 2;   // 16.8 MB
    uint16_t* WinT    = (uint16_t*)(ws + off); off += (size_t)4096 * 1024 * 2;      //  8.4 MB
    uint16_t* WoutT   = (uint16_t*)(ws + off); off += (size_t)1024 * 2048 * 2;      //  4.2 MB
    uint16_t* WxT     = (uint16_t*)(ws + off); off += (size_t)128 * 2048 * 2;       //  0.5 MB
    uint16_t* WdtT    = (uint16_t*)(ws + off); off += (size_t)2048 * 64 * 2;        //  0.26 MB
    uint16_t* z16     = (uint16_t*)(ws + off); off += (size_t)MROWS * 4096 * 2;     // 67 MB (u_raw | res)
    uint16_t* u16     = (uint16_t*)(ws + off); off += (size_t)MROWS * DINNER * 2;   // 33.5 MB
    float*    xdbl    = (float*)(ws + off);    off += (size_t)MROWS * 96 * 4;       //  3.1 MB
    uint16_t* dr16    = (uint16_t*)(ws + off); off += (size_t)MROWS * 64 * 2;       //  1.0 MB
    uint16_t* delta16 = (uint16_t*)(ws + off); off += (size_t)MROWS * DINNER * 2;   // 33.5 MB
    uint16_t* y16     = (uint16_t*)(ws + off); off += (size_t)MROWS * DINNER * 2;   // 33.5 MB

    // xb16 (16.8 MB) is dead after in_proj; it hosts, in sequence:
    //   1) xpart: split-K partials of x_proj, 4 * 8192*96*4B = 12.6 MB
    //   2) Pws+Qws: 2 * 16*4*2048*16*4B = 16.8 MB (H0 in-place in Pws)
    float* xpart = (float*)xb16;
    float* Pws   = (float*)xb16;
    float* Qws   = Pws + (size_t)NCHUNK * BATCH * DINNER * DSTATE;

    dim3 tb(32, 8);
    convert_x_kernel<<<MROWS, 256, 0, stream>>>(x, xb16);
    transpose_cvt_kernel<<<dim3(32, 128), tb, 0, stream>>>(W_in,  WinT,  1024, 4096, 4096);
    transpose_cvt_kernel<<<dim3(64, 32),  tb, 0, stream>>>(W_out, WoutT, 2048, 1024, 1024);
    transpose_cvt_kernel<<<dim3(64, 4),   tb, 0, stream>>>(W_x,   WxT,   2048, 96, 128);
    transpose_cvt_kernel<<<dim3(2, 64),   tb, 0, stream>>>(W_dt,  WdtT,  64, 2048, 2048);

    // z = X @ W_in   (8192 x 4096 x 1024)
    gemm_bt_kernel<EPI_BF16, false><<<dim3(64, 32), 256, 0, stream>>>(
        xb16, WinT, z16, nullptr, 4096, 1024, 4096, 0);
    // u = silu(causal depthwise conv(z_u) + cb)   [register sliding window]
    conv_silu_kernel<<<MROWS / CROWS, 256, 0, stream>>>(z16, cw, cb, u16);
    // x_dbl partials = u @ W_x   (8192 x 96 x 2048), split-K x4
    gemm_bt_kernel<EPI_F32G, true><<<dim3(64, 1, 4), 256, 0, stream>>>(
        u16, WxT, xpart, nullptr, 96, 2048, 96, 512);
    // reduce partials -> xdbl fp32 + dr16 bf16
    reduce_xdbl_kernel<<<MROWS, 128, 0, stream>>>(xpart, xdbl, dr16);
    // delta = softplus(delta_raw @ W_dt + b_dt)   (8192 x 2048 x 64)
    gemm_bt_kernel<EPI_SP, false><<<dim3(64, 16), 256, 0, stream>>>(
        dr16, WdtT, delta16, b_dt, 2048, 64, 2048, 0);

    // chunked selective scan, n-split register-resident states
    scan_part1_kernel<<<dim3(DINNER / 128, BATCH, NCHUNK), 256, 0, stream>>>(
        delta16, u16, xdbl, A_log, Pws, Qws);
    scan_combine_kernel<<<BATCH * DINNER * DSTATE / 256, 256, 0, stream>>>(
        Pws, Qws);
    scan_part3_kernel<<<dim3(DINNER / 128, BATCH, NCHUNK), 256, 0, stream>>>(
        delta16, u16, xdbl, z16, A_log, Dv, Pws, y16);

    // out = y @ W_out   (8192 x 1024 x 2048), remapped to (t,b,c) fp32
    gemm_bt_kernel<EPI_REMAP, false><<<dim3(64, 8), 256, 0, stream>>>(
        y16, WoutT, d_out, nullptr, 1024, 2048, 1024, 0);
}

// Round 6
// 420.214 us; speedup vs baseline: 1.3289x; 1.3289x over previous
//
#include <hip/hip_runtime.h>
#include <hip/hip_bf16.h>
#include <stdint.h>

#define T_LEN   2048
#define BATCH   4
#define DMODEL  1024
#define DINNER  2048
#define DSTATE  16
#define DTRANK  64
#define MROWS   (BATCH*T_LEN)   // 8192
#define NCHUNK  16
#define CLEN    (T_LEN / NCHUNK)  // 128
#define PF      8                 // scan prefetch depth

typedef __bf16 bf16x8_t __attribute__((ext_vector_type(8)));
typedef float  f32x4_t  __attribute__((ext_vector_type(4)));

__device__ __forceinline__ uint16_t f2b(float f) {
    uint32_t u = __float_as_uint(f);
    u += 0x7fffu + ((u >> 16) & 1u);          // round-to-nearest-even
    return (uint16_t)(u >> 16);
}
__device__ __forceinline__ float b2f(uint16_t h) {
    return __uint_as_float(((uint32_t)h) << 16);
}

// async global->LDS, 16B per lane (m97 recipe)
__device__ __forceinline__ void gload16(const void* g, void* l) {
    __builtin_amdgcn_global_load_lds(
        (const __attribute__((address_space(1))) void*)g,
        (__attribute__((address_space(3))) void*)l, 16, 0, 0);
}

// ---------------------------------------------------------------------------
// x (t,b,c) fp32  ->  xb16 (b*T+t, c) bf16   (permute + convert)
// ---------------------------------------------------------------------------
__global__ __launch_bounds__(256) void convert_x_kernel(
    const float* __restrict__ x, uint16_t* __restrict__ xb)
{
    int tb = blockIdx.x;            // 0..8191, = t*4 + b
    int t = tb >> 2, b = tb & 3;
    int c = threadIdx.x * 4;
    const float4 v = *(const float4*)(x + ((size_t)tb) * DMODEL + c);
    uint16_t* dst = xb + ((size_t)(b * T_LEN + t)) * DMODEL + c;
    uint2 p;
    p.x = (uint32_t)f2b(v.x) | ((uint32_t)f2b(v.y) << 16);
    p.y = (uint32_t)f2b(v.z) | ((uint32_t)f2b(v.w) << 16);
    *(uint2*)dst = p;
}

// ---------------------------------------------------------------------------
// transpose + convert: src fp32 [R][C] -> dst bf16 [Cpad][R], zero-fill c>=C
// ---------------------------------------------------------------------------
__global__ __launch_bounds__(256) void transpose_cvt_kernel(
    const float* __restrict__ src, uint16_t* __restrict__ dst,
    int R, int C, int Cpad)
{
    __shared__ float tile[32][33];
    int r0 = blockIdx.x * 32;
    int c0 = blockIdx.y * 32;
    int tx = threadIdx.x, ty = threadIdx.y;
#pragma unroll
    for (int i = 0; i < 32; i += 8) {
        int r = r0 + ty + i, c = c0 + tx;
        tile[ty + i][tx] = (r < R && c < C) ? src[(size_t)r * C + c] : 0.f;
    }
    __syncthreads();
#pragma unroll
    for (int i = 0; i < 32; i += 8) {
        int dr = c0 + ty + i;   // dst row = src col
        int dc = r0 + tx;       // dst col = src row
        if (dr < Cpad && dc < R) dst[(size_t)dr * R + dc] = f2b(tile[tx][ty + i]);
    }
}

// ---------------------------------------------------------------------------
// Generic bf16 MFMA GEMM: C[M][N] = A[M][K] * Bt[N][K]^T
// global_load_lds width-16 staging (m97 structure)
// ---------------------------------------------------------------------------
#define EPI_BF16  0
#define EPI_F32G  1
#define EPI_SP    2
#define EPI_REMAP 3

template <int EPI, bool SPLITK>
__global__ __launch_bounds__(256) void gemm_bt_kernel(
    const uint16_t* __restrict__ A, const uint16_t* __restrict__ Bt,
    void* __restrict__ CoutBase, const float* __restrict__ bias,
    int N, int K, int ldc, int ksplit)
{
    __shared__ uint16_t As[128 * 32];
    __shared__ uint16_t Bs[128 * 32];

    int tid = threadIdx.x;
    int bm = blockIdx.x * 128, bn = blockIdx.y * 128;
    int kbeg = SPLITK ? blockIdx.z * ksplit : 0;
    int kend = SPLITK ? kbeg + ksplit : K;
    void* Cout = SPLITK
        ? (void*)((float*)CoutBase + (size_t)blockIdx.z * MROWS * ldc)
        : CoutBase;

    const uint16_t* ap0 = A  + (size_t)(bm + (tid >> 2)) * K + kbeg + (tid & 3) * 8;
    const uint16_t* ap1 = ap0 + (size_t)64 * K;
    const uint16_t* bp0 = Bt + (size_t)(bn + (tid >> 2)) * K + kbeg + (tid & 3) * 8;
    const uint16_t* bp1 = bp0 + (size_t)64 * K;

    f32x4_t acc[4][4];
#pragma unroll
    for (int i = 0; i < 4; i++)
#pragma unroll
        for (int j = 0; j < 4; j++) acc[i][j] = (f32x4_t){0.f, 0.f, 0.f, 0.f};

    int wid = tid >> 6, lane = tid & 63;
    int wm = (wid & 1) * 64, wn = (wid >> 1) * 64;
    int lr = lane & 15, lq = lane >> 4;
    const uint16_t* Afrag = &As[(wm + lr) * 32 + lq * 8];
    const uint16_t* Bfrag = &Bs[(wn + lr) * 32 + lq * 8];

    for (int k0 = kbeg; k0 < kend; k0 += 32) {
        __syncthreads();                       // LDS safe to overwrite
        gload16(ap0, &As[(size_t)tid * 8]);
        gload16(ap1, &As[(size_t)(tid + 256) * 8]);
        gload16(bp0, &Bs[(size_t)tid * 8]);
        gload16(bp1, &Bs[(size_t)(tid + 256) * 8]);
        ap0 += 32; ap1 += 32; bp0 += 32; bp1 += 32;
        __syncthreads();                       // drains vmcnt (async LDS stores)

        bf16x8_t av[4], bv[4];
#pragma unroll
        for (int i = 0; i < 4; i++) av[i] = *(const bf16x8_t*)(Afrag + i * 512);
#pragma unroll
        for (int j = 0; j < 4; j++) bv[j] = *(const bf16x8_t*)(Bfrag + j * 512);
#pragma unroll
        for (int i = 0; i < 4; i++)
#pragma unroll
            for (int j = 0; j < 4; j++)
                acc[i][j] = __builtin_amdgcn_mfma_f32_16x16x32_bf16(
                    av[i], bv[j], acc[i][j], 0, 0, 0);
    }

#pragma unroll
    for (int i = 0; i < 4; i++) {
#pragma unroll
        for (int j = 0; j < 4; j++) {
            int col = bn + wn + j * 16 + lr;
#pragma unroll
            for (int r = 0; r < 4; r++) {
                int row = bm + wm + i * 16 + lq * 4 + r;
                float v = acc[i][j][r];
                if (EPI == EPI_BF16) {
                    ((uint16_t*)Cout)[(size_t)row * ldc + col] = f2b(v);
                } else if (EPI == EPI_F32G) {
                    if (col < N) ((float*)Cout)[(size_t)row * ldc + col] = v;
                } else if (EPI == EPI_SP) {
                    float xv = v + bias[col];
                    float sp = (xv > 15.f) ? xv : __logf(1.f + __expf(xv));
                    ((uint16_t*)Cout)[(size_t)row * ldc + col] = f2b(sp);
                } else {
                    int bb = row >> 11, tt = row & (T_LEN - 1);
                    ((float*)Cout)[((size_t)(tt * BATCH + bb)) * ldc + col] = v;
                }
            }
        }
    }
}

// ---------------------------------------------------------------------------
// depthwise causal conv (width 4) + bias + SiLU — register sliding window.
// ---------------------------------------------------------------------------
#define CROWS 16

__global__ __launch_bounds__(256) void conv_silu_kernel(
    const uint16_t* __restrict__ z, const float* __restrict__ cw,
    const float* __restrict__ cb, uint16_t* __restrict__ u)
{
    int c0 = threadIdx.x * 8;           // 0..2040
    int m0 = blockIdx.x * CROWS;

    float w[8][4], bias[8];
#pragma unroll
    for (int c = 0; c < 8; ++c)
        *(float4*)w[c] = *(const float4*)(cw + (size_t)(c0 + c) * 4);
    *(float4*)&bias[0] = *(const float4*)(cb + c0);
    *(float4*)&bias[4] = *(const float4*)(cb + c0 + 4);

    float fw[4][8];
    bool seqstart = (m0 & (T_LEN - 1)) == 0;
#pragma unroll
    for (int j = 0; j < 3; ++j) {
        int m = m0 - 3 + j;
        if (seqstart) {
#pragma unroll
            for (int c = 0; c < 8; ++c) fw[j + 1][c] = 0.f;
        } else {
            uint4 v = *(const uint4*)(z + (size_t)m * 4096 + c0);
            fw[j + 1][0] = b2f((uint16_t)(v.x & 0xffff)); fw[j + 1][1] = b2f((uint16_t)(v.x >> 16));
            fw[j + 1][2] = b2f((uint16_t)(v.y & 0xffff)); fw[j + 1][3] = b2f((uint16_t)(v.y >> 16));
            fw[j + 1][4] = b2f((uint16_t)(v.z & 0xffff)); fw[j + 1][5] = b2f((uint16_t)(v.z >> 16));
            fw[j + 1][6] = b2f((uint16_t)(v.w & 0xffff)); fw[j + 1][7] = b2f((uint16_t)(v.w >> 16));
        }
    }

#pragma unroll
    for (int t = 0; t < CROWS; ++t) {
        int m = m0 + t;
        int s = t & 3;
        uint4 v = *(const uint4*)(z + (size_t)m * 4096 + c0);
        fw[s][0] = b2f((uint16_t)(v.x & 0xffff)); fw[s][1] = b2f((uint16_t)(v.x >> 16));
        fw[s][2] = b2f((uint16_t)(v.y & 0xffff)); fw[s][3] = b2f((uint16_t)(v.y >> 16));
        fw[s][4] = b2f((uint16_t)(v.z & 0xffff)); fw[s][5] = b2f((uint16_t)(v.z >> 16));
        fw[s][6] = b2f((uint16_t)(v.w & 0xffff)); fw[s][7] = b2f((uint16_t)(v.w >> 16));
        uint16_t out[8];
#pragma unroll
        for (int c = 0; c < 8; ++c) {
            float a = bias[c];
#pragma unroll
            for (int j = 0; j < 4; ++j)
                a = fmaf(fw[(t + 1 + j) & 3][c], w[c][j], a);
            float sv = a / (1.f + __expf(-a));
            out[c] = f2b(sv);
        }
        uint4 o;
        o.x = (uint32_t)out[0] | ((uint32_t)out[1] << 16);
        o.y = (uint32_t)out[2] | ((uint32_t)out[3] << 16);
        o.z = (uint32_t)out[4] | ((uint32_t)out[5] << 16);
        o.w = (uint32_t)out[6] | ((uint32_t)out[7] << 16);
        *(uint4*)(u + (size_t)m * DINNER + c0) = o;
    }
}

// ---------------------------------------------------------------------------
// reduce split-K partials of x_proj: xdbl = sum_z xpart[z], dr16 = bf16(cols<64)
// ---------------------------------------------------------------------------
__global__ __launch_bounds__(128) void reduce_xdbl_kernel(
    const float* __restrict__ xpart, float* __restrict__ xdbl,
    uint16_t* __restrict__ dr16)
{
    int m = blockIdx.x, r = threadIdx.x;
    if (r >= 96) return;
    const size_t stride = (size_t)MROWS * 96;
    size_t idx = (size_t)m * 96 + r;
    float s = xpart[idx] + xpart[stride + idx]
            + xpart[2 * stride + idx] + xpart[3 * stride + idx];
    xdbl[idx] = s;
    if (r < DTRANK) dr16[(size_t)m * DTRANK + r] = f2b(s);
}

// ---------------------------------------------------------------------------
// CHUNKED SELECTIVE SCAN, thread = (b, d, chunk), 16 n-states in regs.
// R5 lessons: n-split shuffle regressed (per-step cross-lane sync) — revert.
// R4 counters showed 965 cy/step = load-latency serialized. Fixes here:
//   * delta/u/rg prefetched PF=8 deep in rotating register slots
//   * B/C rows staged in LDS once per block (uniform ds_read thereafter)
//   * P-product via exp2(ae*sum(delta)) once per chunk (any A)
//   * fast path: A[n] = -(n+1)*A[0] (true for this model's A_log) ->
//     w_n = q^(n+1), 1 exp2 + 15 muls/step, behind a uniform runtime guard
// ---------------------------------------------------------------------------
#define LOG2E 1.44269504088896340736f

__global__ __launch_bounds__(256) void scan_part1_kernel(
    const uint16_t* __restrict__ delta16, const uint16_t* __restrict__ u16,
    const float* __restrict__ xdbl, const float* __restrict__ A_log,
    float* __restrict__ Pws, float* __restrict__ Qws)
{
    __shared__ float lds_b[CLEN][16];
    int tid = threadIdx.x;
    int d = blockIdx.x * 256 + tid;
    int b = blockIdx.y, c = blockIdx.z;
    size_t mbase = (size_t)b * T_LEN + (size_t)c * CLEN;

    // stage B rows (xdbl cols 64..79) into LDS: 128 rows x 16 floats
    {
        int r = tid >> 1, pair = tid & 1;
        const float4* src = (const float4*)(xdbl + (mbase + r) * 96 + 64 + pair * 8);
        float4* dst = (float4*)&lds_b[r][pair * 8];
        dst[0] = src[0]; dst[1] = src[1];
    }

    float ae[DSTATE];
#pragma unroll
    for (int n = 0; n < DSTATE; ++n)
        ae[n] = -__expf(A_log[d * DSTATE + n]) * LOG2E;
    bool fastexp = true;
#pragma unroll
    for (int n = 1; n < DSTATE; ++n)
        fastexp = fastexp && (fabsf(ae[n] - (n + 1) * ae[0]) <= 1e-4f * fabsf(ae[n]));

    float h[DSTATE];
#pragma unroll
    for (int n = 0; n < DSTATE; ++n) h[n] = 0.f;
    float sdelta = 0.f;

    uint16_t dpf[PF], upf[PF];
#pragma unroll
    for (int t = 0; t < PF; ++t) {
        size_t m = mbase + t;
        dpf[t] = delta16[m * DINNER + d];
        upf[t] = u16[m * DINNER + d];
    }
    __syncthreads();

    if (fastexp) {
#pragma unroll 8
        for (int t = 0; t < CLEN; ++t) {
            int slot = t & (PF - 1);
            float delta = b2f(dpf[slot]);
            float du    = delta * b2f(upf[slot]);
            int tn = t + PF; tn = tn < CLEN ? tn : CLEN - 1;
            size_t mn = mbase + tn;
            dpf[slot] = delta16[mn * DINNER + d];
            upf[slot] = u16[mn * DINNER + d];
            float Bv[DSTATE];
            *(float4*)&Bv[0]  = *(const float4*)&lds_b[t][0];
            *(float4*)&Bv[4]  = *(const float4*)&lds_b[t][4];
            *(float4*)&Bv[8]  = *(const float4*)&lds_b[t][8];
            *(float4*)&Bv[12] = *(const float4*)&lds_b[t][12];
            float q = __builtin_amdgcn_exp2f(delta * ae[0]);
            float w = 1.f;
            sdelta += delta;
#pragma unroll
            for (int n = 0; n < DSTATE; ++n) {
                w *= q;
                h[n] = fmaf(w, h[n], du * Bv[n]);
            }
        }
    } else {
#pragma unroll 8
        for (int t = 0; t < CLEN; ++t) {
            int slot = t & (PF - 1);
            float delta = b2f(dpf[slot]);
            float du    = delta * b2f(upf[slot]);
            int tn = t + PF; tn = tn < CLEN ? tn : CLEN - 1;
            size_t mn = mbase + tn;
            dpf[slot] = delta16[mn * DINNER + d];
            upf[slot] = u16[mn * DINNER + d];
            float Bv[DSTATE];
            *(float4*)&Bv[0]  = *(const float4*)&lds_b[t][0];
            *(float4*)&Bv[4]  = *(const float4*)&lds_b[t][4];
            *(float4*)&Bv[8]  = *(const float4*)&lds_b[t][8];
            *(float4*)&Bv[12] = *(const float4*)&lds_b[t][12];
            sdelta += delta;
#pragma unroll
            for (int n = 0; n < DSTATE; ++n) {
                float w = __builtin_amdgcn_exp2f(delta * ae[n]);
                h[n] = fmaf(w, h[n], du * Bv[n]);
            }
        }
    }

    float P[DSTATE];
#pragma unroll
    for (int n = 0; n < DSTATE; ++n)
        P[n] = __builtin_amdgcn_exp2f(ae[n] * sdelta);
    float* Pp = Pws + (((size_t)c * BATCH + b) * DINNER + d) * DSTATE;
    float* Qp = Qws + (((size_t)c * BATCH + b) * DINNER + d) * DSTATE;
#pragma unroll
    for (int n = 0; n < DSTATE; n += 4) {
        *(float4*)(Pp + n) = *(float4*)&P[n];
        *(float4*)(Qp + n) = *(float4*)&h[n];
    }
}

// in-place: H0 for chunk c overwrites Pws[c]
__global__ __launch_bounds__(256) void scan_combine_kernel(
    float* __restrict__ Pws, const float* __restrict__ Qws)
{
    size_t i = (size_t)blockIdx.x * 256 + threadIdx.x;  // BATCH*DINNER*DSTATE
    const size_t stride = (size_t)BATCH * DINNER * DSTATE;
    float h = 0.f;
#pragma unroll
    for (int c = 0; c < NCHUNK; ++c) {
        float P = Pws[c * stride + i];
        float Q = Qws[c * stride + i];
        Pws[c * stride + i] = h;        // chunk-c initial state
        h = fmaf(P, h, Q);
    }
}

__global__ __launch_bounds__(256) void scan_part3_kernel(
    const uint16_t* __restrict__ delta16, const uint16_t* __restrict__ u16,
    const float* __restrict__ xdbl, const uint16_t* __restrict__ z16,
    const float* __restrict__ A_log, const float* __restrict__ Dvec,
    const float* __restrict__ H0ws, uint16_t* __restrict__ y16)
{
    __shared__ float lds_bc[CLEN][32];
    int tid = threadIdx.x;
    int d = blockIdx.x * 256 + tid;
    int b = blockIdx.y, c = blockIdx.z;
    size_t mbase = (size_t)b * T_LEN + (size_t)c * CLEN;

    // stage B+C rows (xdbl cols 64..95) into LDS: 128 rows x 32 floats
    {
        int r = tid >> 1, half = tid & 1;
        const float4* src = (const float4*)(xdbl + (mbase + r) * 96 + 64 + half * 16);
        float4* dst = (float4*)&lds_bc[r][half * 16];
        dst[0] = src[0]; dst[1] = src[1]; dst[2] = src[2]; dst[3] = src[3];
    }

    float ae[DSTATE];
#pragma unroll
    for (int n = 0; n < DSTATE; ++n)
        ae[n] = -__expf(A_log[d * DSTATE + n]) * LOG2E;
    bool fastexp = true;
#pragma unroll
    for (int n = 1; n < DSTATE; ++n)
        fastexp = fastexp && (fabsf(ae[n] - (n + 1) * ae[0]) <= 1e-4f * fabsf(ae[n]));
    float Dd = Dvec[d];

    float h[DSTATE];
    size_t hbase = (((size_t)c * BATCH + b) * DINNER + d) * DSTATE;
#pragma unroll
    for (int n = 0; n < DSTATE; n += 4)
        *(float4*)&h[n] = *(const float4*)(H0ws + hbase + n);

    uint16_t dpf[PF], upf[PF], rpf[PF];
#pragma unroll
    for (int t = 0; t < PF; ++t) {
        size_t m = mbase + t;
        dpf[t] = delta16[m * DINNER + d];
        upf[t] = u16[m * DINNER + d];
        rpf[t] = z16[m * 4096 + DINNER + d];
    }
    __syncthreads();

    if (fastexp) {
#pragma unroll 8
        for (int t = 0; t < CLEN; ++t) {
            int slot = t & (PF - 1);
            float delta = b2f(dpf[slot]);
            float uu    = b2f(upf[slot]);
            float rg    = b2f(rpf[slot]);
            int tn = t + PF; tn = tn < CLEN ? tn : CLEN - 1;
            size_t mn = mbase + tn;
            dpf[slot] = delta16[mn * DINNER + d];
            upf[slot] = u16[mn * DINNER + d];
            rpf[slot] = z16[mn * 4096 + DINNER + d];
            float du = delta * uu;
            float Bv[DSTATE], Cv[DSTATE];
            *(float4*)&Bv[0]  = *(const float4*)&lds_bc[t][0];
            *(float4*)&Bv[4]  = *(const float4*)&lds_bc[t][4];
            *(float4*)&Bv[8]  = *(const float4*)&lds_bc[t][8];
            *(float4*)&Bv[12] = *(const float4*)&lds_bc[t][12];
            *(float4*)&Cv[0]  = *(const float4*)&lds_bc[t][16];
            *(float4*)&Cv[4]  = *(const float4*)&lds_bc[t][20];
            *(float4*)&Cv[8]  = *(const float4*)&lds_bc[t][24];
            *(float4*)&Cv[12] = *(const float4*)&lds_bc[t][28];
            float q = __builtin_amdgcn_exp2f(delta * ae[0]);
            float w = 1.f, y = 0.f;
#pragma unroll
            for (int n = 0; n < DSTATE; ++n) {
                w *= q;
                h[n] = fmaf(w, h[n], du * Bv[n]);
                y = fmaf(h[n], Cv[n], y);
            }
            y = fmaf(uu, Dd, y);
            float sig = 1.f / (1.f + __expf(-rg));
            y16[(mbase + t) * DINNER + d] = f2b(y * rg * sig);
        }
    } else {
#pragma unroll 8
        for (int t = 0; t < CLEN; ++t) {
            int slot = t & (PF - 1);
            float delta = b2f(dpf[slot]);
            float uu    = b2f(upf[slot]);
            float rg    = b2f(rpf[slot]);
            int tn = t + PF; tn = tn < CLEN ? tn : CLEN - 1;
            size_t mn = mbase + tn;
            dpf[slot] = delta16[mn * DINNER + d];
            upf[slot] = u16[mn * DINNER + d];
            rpf[slot] = z16[mn * 4096 + DINNER + d];
            float du = delta * uu;
            float Bv[DSTATE], Cv[DSTATE];
            *(float4*)&Bv[0]  = *(const float4*)&lds_bc[t][0];
            *(float4*)&Bv[4]  = *(const float4*)&lds_bc[t][4];
            *(float4*)&Bv[8]  = *(const float4*)&lds_bc[t][8];
            *(float4*)&Bv[12] = *(const float4*)&lds_bc[t][12];
            *(float4*)&Cv[0]  = *(const float4*)&lds_bc[t][16];
            *(float4*)&Cv[4]  = *(const float4*)&lds_bc[t][20];
            *(float4*)&Cv[8]  = *(const float4*)&lds_bc[t][24];
            *(float4*)&Cv[12] = *(const float4*)&lds_bc[t][28];
            float y = 0.f;
#pragma unroll
            for (int n = 0; n < DSTATE; ++n) {
                float w = __builtin_amdgcn_exp2f(delta * ae[n]);
                h[n] = fmaf(w, h[n], du * Bv[n]);
                y = fmaf(h[n], Cv[n], y);
            }
            y = fmaf(uu, Dd, y);
            float sig = 1.f / (1.f + __expf(-rg));
            y16[(mbase + t) * DINNER + d] = f2b(y * rg * sig);
        }
    }
}

// ---------------------------------------------------------------------------
extern "C" void kernel_launch(void* const* d_in, const int* in_sizes, int n_in,
                              void* d_out, int out_size, void* d_ws, size_t ws_size,
                              hipStream_t stream)
{
    const float* x     = (const float*)d_in[0];
    const float* W_in  = (const float*)d_in[1];
    const float* cw    = (const float*)d_in[2];
    const float* cb    = (const float*)d_in[3];
    const float* W_x   = (const float*)d_in[4];
    const float* W_dt  = (const float*)d_in[5];
    const float* b_dt  = (const float*)d_in[6];
    const float* A_log = (const float*)d_in[7];
    const float* Dv    = (const float*)d_in[8];
    const float* W_out = (const float*)d_in[9];

    char* ws = (char*)d_ws;
    size_t off = 0;
    uint16_t* xb16    = (uint16_t*)(ws + off); off += (size_t)MROWS * DMODEL * 2;   // 16.8 MB
    uint16_t* WinT    = (uint16_t*)(ws + off); off += (size_t)4096 * 1024 * 2;      //  8.4 MB
    uint16_t* WoutT   = (uint16_t*)(ws + off); off += (size_t)1024 * 2048 * 2;      //  4.2 MB
    uint16_t* WxT     = (uint16_t*)(ws + off); off += (size_t)128 * 2048 * 2;       //  0.5 MB
    uint16_t* WdtT    = (uint16_t*)(ws + off); off += (size_t)2048 * 64 * 2;        //  0.26 MB
    uint16_t* z16     = (uint16_t*)(ws + off); off += (size_t)MROWS * 4096 * 2;     // 67 MB (u_raw | res)
    uint16_t* u16     = (uint16_t*)(ws + off); off += (size_t)MROWS * DINNER * 2;   // 33.5 MB
    float*    xdbl    = (float*)(ws + off);    off += (size_t)MROWS * 96 * 4;       //  3.1 MB
    uint16_t* dr16    = (uint16_t*)(ws + off); off += (size_t)MROWS * 64 * 2;       //  1.0 MB
    uint16_t* delta16 = (uint16_t*)(ws + off); off += (size_t)MROWS * DINNER * 2;   // 33.5 MB
    uint16_t* y16     = (uint16_t*)(ws + off); off += (size_t)MROWS * DINNER * 2;   // 33.5 MB

    // xb16 (16.8 MB) is dead after in_proj; it hosts, in sequence:
    //   1) xpart: split-K partials of x_proj, 4 * 8192*96*4B = 12.6 MB
    //   2) Pws+Qws: 2 * 16*4*2048*16*4B = 16.8 MB (H0 in-place in Pws)
    float* xpart = (float*)xb16;
    float* Pws   = (float*)xb16;
    float* Qws   = Pws + (size_t)NCHUNK * BATCH * DINNER * DSTATE;

    dim3 tb(32, 8);
    convert_x_kernel<<<MROWS, 256, 0, stream>>>(x, xb16);
    transpose_cvt_kernel<<<dim3(32, 128), tb, 0, stream>>>(W_in,  WinT,  1024, 4096, 4096);
    transpose_cvt_kernel<<<dim3(64, 32),  tb, 0, stream>>>(W_out, WoutT, 2048, 1024, 1024);
    transpose_cvt_kernel<<<dim3(64, 4),   tb, 0, stream>>>(W_x,   WxT,   2048, 96, 128);
    transpose_cvt_kernel<<<dim3(2, 64),   tb, 0, stream>>>(W_dt,  WdtT,  64, 2048, 2048);

    // z = X @ W_in   (8192 x 4096 x 1024)
    gemm_bt_kernel<EPI_BF16, false><<<dim3(64, 32), 256, 0, stream>>>(
        xb16, WinT, z16, nullptr, 4096, 1024, 4096, 0);
    // u = silu(causal depthwise conv(z_u) + cb)   [register sliding window]
    conv_silu_kernel<<<MROWS / CROWS, 256, 0, stream>>>(z16, cw, cb, u16);
    // x_dbl partials = u @ W_x   (8192 x 96 x 2048), split-K x4
    gemm_bt_kernel<EPI_F32G, true><<<dim3(64, 1, 4), 256, 0, stream>>>(
        u16, WxT, xpart, nullptr, 96, 2048, 96, 512);
    // reduce partials -> xdbl fp32 + dr16 bf16
    reduce_xdbl_kernel<<<MROWS, 128, 0, stream>>>(xpart, xdbl, dr16);
    // delta = softplus(delta_raw @ W_dt + b_dt)   (8192 x 2048 x 64)
    gemm_bt_kernel<EPI_SP, false><<<dim3(64, 16), 256, 0, stream>>>(
        dr16, WdtT, delta16, b_dt, 2048, 64, 2048, 0);

    // chunked selective scan, register-resident states, PF-deep prefetch
    scan_part1_kernel<<<dim3(DINNER / 256, BATCH, NCHUNK), 256, 0, stream>>>(
        delta16, u16, xdbl, A_log, Pws, Qws);
    scan_combine_kernel<<<BATCH * DINNER * DSTATE / 256, 256, 0, stream>>>(
        Pws, Qws);
    scan_part3_kernel<<<dim3(DINNER / 256, BATCH, NCHUNK), 256, 0, stream>>>(
        delta16, u16, xdbl, z16, A_log, Dv, Pws, y16);

    // out = y @ W_out   (8192 x 1024 x 2048), remapped to (t,b,c) fp32
    gemm_bt_kernel<EPI_REMAP, false><<<dim3(64, 8), 256, 0, stream>>>(
        y16, WoutT, d_out, nullptr, 1024, 2048, 1024, 0);
}

// Round 7
// 416.679 us; speedup vs baseline: 1.3402x; 1.0085x over previous
//
#include <hip/hip_runtime.h>
#include <hip/hip_bf16.h>
#include <stdint.h>

#define T_LEN   2048
#define BATCH   4
#define DMODEL  1024
#define DINNER  2048
#define DSTATE  16
#define DTRANK  64
#define MROWS   (BATCH*T_LEN)   // 8192
#define NCHUNK  16
#define CLEN    (T_LEN / NCHUNK)  // 128
#define PF      8                 // scan prefetch depth

typedef __bf16 bf16x8_t __attribute__((ext_vector_type(8)));
typedef float  f32x4_t  __attribute__((ext_vector_type(4)));

__device__ __forceinline__ uint16_t f2b(float f) {
    uint32_t u = __float_as_uint(f);
    u += 0x7fffu + ((u >> 16) & 1u);          // round-to-nearest-even
    return (uint16_t)(u >> 16);
}
__device__ __forceinline__ float b2f(uint16_t h) {
    return __uint_as_float(((uint32_t)h) << 16);
}

// async global->LDS, 16B per lane (m97 recipe)
__device__ __forceinline__ void gload16(const void* g, void* l) {
    __builtin_amdgcn_global_load_lds(
        (const __attribute__((address_space(1))) void*)g,
        (__attribute__((address_space(3))) void*)l, 16, 0, 0);
}

// ---------------------------------------------------------------------------
// x (t,b,c) fp32  ->  xb16 (b*T+t, c) bf16   (permute + convert)
// ---------------------------------------------------------------------------
__global__ __launch_bounds__(256) void convert_x_kernel(
    const float* __restrict__ x, uint16_t* __restrict__ xb)
{
    int tb = blockIdx.x;            // 0..8191, = t*4 + b
    int t = tb >> 2, b = tb & 3;
    int c = threadIdx.x * 4;
    const float4 v = *(const float4*)(x + ((size_t)tb) * DMODEL + c);
    uint16_t* dst = xb + ((size_t)(b * T_LEN + t)) * DMODEL + c;
    uint2 p;
    p.x = (uint32_t)f2b(v.x) | ((uint32_t)f2b(v.y) << 16);
    p.y = (uint32_t)f2b(v.z) | ((uint32_t)f2b(v.w) << 16);
    *(uint2*)dst = p;
}

// ---------------------------------------------------------------------------
// transpose + convert: src fp32 [R][C] -> dst bf16 [Cpad][R], zero-fill c>=C
// ---------------------------------------------------------------------------
__global__ __launch_bounds__(256) void transpose_cvt_kernel(
    const float* __restrict__ src, uint16_t* __restrict__ dst,
    int R, int C, int Cpad)
{
    __shared__ float tile[32][33];
    int r0 = blockIdx.x * 32;
    int c0 = blockIdx.y * 32;
    int tx = threadIdx.x, ty = threadIdx.y;
#pragma unroll
    for (int i = 0; i < 32; i += 8) {
        int r = r0 + ty + i, c = c0 + tx;
        tile[ty + i][tx] = (r < R && c < C) ? src[(size_t)r * C + c] : 0.f;
    }
    __syncthreads();
#pragma unroll
    for (int i = 0; i < 32; i += 8) {
        int dr = c0 + ty + i;   // dst row = src col
        int dc = r0 + tx;       // dst col = src row
        if (dr < Cpad && dc < R) dst[(size_t)dr * R + dc] = f2b(tile[tx][ty + i]);
    }
}

// ---------------------------------------------------------------------------
// Generic bf16 MFMA GEMM: C[M][N] = A[M][K] * Bt[N][K]^T
// global_load_lds width-16 staging + XOR-swizzled LDS chunks:
//   lane tid fetches row tid>>2, kchunk (tid&3)^((row>>1)&3)  (still 64B-
//   contiguous per 4 lanes); fragment reads then start on banks
//   {0,4,..,28} across lr -> 2-way max per quarter-wave = conflict-free.
// ---------------------------------------------------------------------------
#define EPI_BF16  0
#define EPI_F32G  1
#define EPI_SP    2
#define EPI_REMAP 3

template <int EPI, bool SPLITK>
__global__ __launch_bounds__(256) void gemm_bt_kernel(
    const uint16_t* __restrict__ A, const uint16_t* __restrict__ Bt,
    void* __restrict__ CoutBase, const float* __restrict__ bias,
    int N, int K, int ldc, int ksplit)
{
    __shared__ uint16_t As[128 * 32];
    __shared__ uint16_t Bs[128 * 32];

    int tid = threadIdx.x;
    int bm = blockIdx.x * 128, bn = blockIdx.y * 128;
    int kbeg = SPLITK ? blockIdx.z * ksplit : 0;
    int kend = SPLITK ? kbeg + ksplit : K;
    void* Cout = SPLITK
        ? (void*)((float*)CoutBase + (size_t)blockIdx.z * MROWS * ldc)
        : CoutBase;

    int srow   = tid >> 2;
    int schunk = (tid & 3) ^ ((srow >> 1) & 3);   // XOR swizzle
    const uint16_t* ap0 = A  + (size_t)(bm + srow) * K + kbeg + schunk * 8;
    const uint16_t* ap1 = ap0 + (size_t)64 * K;   // row+64: swizzle invariant
    const uint16_t* bp0 = Bt + (size_t)(bn + srow) * K + kbeg + schunk * 8;
    const uint16_t* bp1 = bp0 + (size_t)64 * K;

    f32x4_t acc[4][4];
#pragma unroll
    for (int i = 0; i < 4; i++)
#pragma unroll
        for (int j = 0; j < 4; j++) acc[i][j] = (f32x4_t){0.f, 0.f, 0.f, 0.f};

    int wid = tid >> 6, lane = tid & 63;
    int wm = (wid & 1) * 64, wn = (wid >> 1) * 64;
    int lr = lane & 15, lq = lane >> 4;
    int fsw = lq ^ ((lr >> 1) & 3);               // fragment chunk swizzle
    const uint16_t* Afrag = &As[(wm + lr) * 32 + fsw * 8];
    const uint16_t* Bfrag = &Bs[(wn + lr) * 32 + fsw * 8];

    for (int k0 = kbeg; k0 < kend; k0 += 32) {
        __syncthreads();                       // LDS safe to overwrite
        gload16(ap0, &As[(size_t)tid * 8]);
        gload16(ap1, &As[(size_t)(tid + 256) * 8]);
        gload16(bp0, &Bs[(size_t)tid * 8]);
        gload16(bp1, &Bs[(size_t)(tid + 256) * 8]);
        ap0 += 32; ap1 += 32; bp0 += 32; bp1 += 32;
        __syncthreads();                       // drains vmcnt (async LDS stores)

        bf16x8_t av[4], bv[4];
#pragma unroll
        for (int i = 0; i < 4; i++) av[i] = *(const bf16x8_t*)(Afrag + i * 512);
#pragma unroll
        for (int j = 0; j < 4; j++) bv[j] = *(const bf16x8_t*)(Bfrag + j * 512);
#pragma unroll
        for (int i = 0; i < 4; i++)
#pragma unroll
            for (int j = 0; j < 4; j++)
                acc[i][j] = __builtin_amdgcn_mfma_f32_16x16x32_bf16(
                    av[i], bv[j], acc[i][j], 0, 0, 0);
    }

#pragma unroll
    for (int i = 0; i < 4; i++) {
#pragma unroll
        for (int j = 0; j < 4; j++) {
            int col = bn + wn + j * 16 + lr;
#pragma unroll
            for (int r = 0; r < 4; r++) {
                int row = bm + wm + i * 16 + lq * 4 + r;
                float v = acc[i][j][r];
                if (EPI == EPI_BF16) {
                    ((uint16_t*)Cout)[(size_t)row * ldc + col] = f2b(v);
                } else if (EPI == EPI_F32G) {
                    if (col < N) ((float*)Cout)[(size_t)row * ldc + col] = v;
                } else if (EPI == EPI_SP) {
                    float xv = v + bias[col];
                    float sp = (xv > 15.f) ? xv : __logf(1.f + __expf(xv));
                    ((uint16_t*)Cout)[(size_t)row * ldc + col] = f2b(sp);
                } else {
                    int bb = row >> 11, tt = row & (T_LEN - 1);
                    ((float*)Cout)[((size_t)(tt * BATCH + bb)) * ldc + col] = v;
                }
            }
        }
    }
}

// ---------------------------------------------------------------------------
// depthwise causal conv (width 4) + bias + SiLU — register sliding window.
// ---------------------------------------------------------------------------
#define CROWS 16

__global__ __launch_bounds__(256) void conv_silu_kernel(
    const uint16_t* __restrict__ z, const float* __restrict__ cw,
    const float* __restrict__ cb, uint16_t* __restrict__ u)
{
    int c0 = threadIdx.x * 8;           // 0..2040
    int m0 = blockIdx.x * CROWS;

    float w[8][4], bias[8];
#pragma unroll
    for (int c = 0; c < 8; ++c)
        *(float4*)w[c] = *(const float4*)(cw + (size_t)(c0 + c) * 4);
    *(float4*)&bias[0] = *(const float4*)(cb + c0);
    *(float4*)&bias[4] = *(const float4*)(cb + c0 + 4);

    float fw[4][8];
    bool seqstart = (m0 & (T_LEN - 1)) == 0;
#pragma unroll
    for (int j = 0; j < 3; ++j) {
        int m = m0 - 3 + j;
        if (seqstart) {
#pragma unroll
            for (int c = 0; c < 8; ++c) fw[j + 1][c] = 0.f;
        } else {
            uint4 v = *(const uint4*)(z + (size_t)m * 4096 + c0);
            fw[j + 1][0] = b2f((uint16_t)(v.x & 0xffff)); fw[j + 1][1] = b2f((uint16_t)(v.x >> 16));
            fw[j + 1][2] = b2f((uint16_t)(v.y & 0xffff)); fw[j + 1][3] = b2f((uint16_t)(v.y >> 16));
            fw[j + 1][4] = b2f((uint16_t)(v.z & 0xffff)); fw[j + 1][5] = b2f((uint16_t)(v.z >> 16));
            fw[j + 1][6] = b2f((uint16_t)(v.w & 0xffff)); fw[j + 1][7] = b2f((uint16_t)(v.w >> 16));
        }
    }

#pragma unroll
    for (int t = 0; t < CROWS; ++t) {
        int m = m0 + t;
        int s = t & 3;
        uint4 v = *(const uint4*)(z + (size_t)m * 4096 + c0);
        fw[s][0] = b2f((uint16_t)(v.x & 0xffff)); fw[s][1] = b2f((uint16_t)(v.x >> 16));
        fw[s][2] = b2f((uint16_t)(v.y & 0xffff)); fw[s][3] = b2f((uint16_t)(v.y >> 16));
        fw[s][4] = b2f((uint16_t)(v.z & 0xffff)); fw[s][5] = b2f((uint16_t)(v.z >> 16));
        fw[s][6] = b2f((uint16_t)(v.w & 0xffff)); fw[s][7] = b2f((uint16_t)(v.w >> 16));
        uint16_t out[8];
#pragma unroll
        for (int c = 0; c < 8; ++c) {
            float a = bias[c];
#pragma unroll
            for (int j = 0; j < 4; ++j)
                a = fmaf(fw[(t + 1 + j) & 3][c], w[c][j], a);
            float sv = a / (1.f + __expf(-a));
            out[c] = f2b(sv);
        }
        uint4 o;
        o.x = (uint32_t)out[0] | ((uint32_t)out[1] << 16);
        o.y = (uint32_t)out[2] | ((uint32_t)out[3] << 16);
        o.z = (uint32_t)out[4] | ((uint32_t)out[5] << 16);
        o.w = (uint32_t)out[6] | ((uint32_t)out[7] << 16);
        *(uint4*)(u + (size_t)m * DINNER + c0) = o;
    }
}

// ---------------------------------------------------------------------------
// reduce split-K partials of x_proj: xdbl = sum_z xpart[z], dr16 = bf16(cols<64)
// ---------------------------------------------------------------------------
__global__ __launch_bounds__(128) void reduce_xdbl_kernel(
    const float* __restrict__ xpart, float* __restrict__ xdbl,
    uint16_t* __restrict__ dr16)
{
    int m = blockIdx.x, r = threadIdx.x;
    if (r >= 96) return;
    const size_t stride = (size_t)MROWS * 96;
    size_t idx = (size_t)m * 96 + r;
    float s = xpart[idx] + xpart[stride + idx]
            + xpart[2 * stride + idx] + xpart[3 * stride + idx];
    xdbl[idx] = s;
    if (r < DTRANK) dr16[(size_t)m * DTRANK + r] = f2b(s);
}

// ---------------------------------------------------------------------------
// CHUNKED SELECTIVE SCAN, thread = (b, d, chunk), 16 n-states in regs.
//   * delta/u/rg prefetched PF=8 deep in rotating register slots
//   * B/C rows staged in LDS once per block (uniform ds_read thereafter)
//   * P-product via exp2(ae*sum(delta)) once per chunk (any A)
//   * fast path: A[n] = -(n+1)*A[0] -> w_n = q^(n+1), behind runtime guard
// ---------------------------------------------------------------------------
#define LOG2E 1.44269504088896340736f

__global__ __launch_bounds__(256) void scan_part1_kernel(
    const uint16_t* __restrict__ delta16, const uint16_t* __restrict__ u16,
    const float* __restrict__ xdbl, const float* __restrict__ A_log,
    float* __restrict__ Pws, float* __restrict__ Qws)
{
    __shared__ float lds_b[CLEN][16];
    int tid = threadIdx.x;
    int d = blockIdx.x * 256 + tid;
    int b = blockIdx.y, c = blockIdx.z;
    size_t mbase = (size_t)b * T_LEN + (size_t)c * CLEN;

    {
        int r = tid >> 1, pair = tid & 1;
        const float4* src = (const float4*)(xdbl + (mbase + r) * 96 + 64 + pair * 8);
        float4* dst = (float4*)&lds_b[r][pair * 8];
        dst[0] = src[0]; dst[1] = src[1];
    }

    float ae[DSTATE];
#pragma unroll
    for (int n = 0; n < DSTATE; ++n)
        ae[n] = -__expf(A_log[d * DSTATE + n]) * LOG2E;
    bool fastexp = true;
#pragma unroll
    for (int n = 1; n < DSTATE; ++n)
        fastexp = fastexp && (fabsf(ae[n] - (n + 1) * ae[0]) <= 1e-4f * fabsf(ae[n]));

    float h[DSTATE];
#pragma unroll
    for (int n = 0; n < DSTATE; ++n) h[n] = 0.f;
    float sdelta = 0.f;

    uint16_t dpf[PF], upf[PF];
#pragma unroll
    for (int t = 0; t < PF; ++t) {
        size_t m = mbase + t;
        dpf[t] = delta16[m * DINNER + d];
        upf[t] = u16[m * DINNER + d];
    }
    __syncthreads();

    if (fastexp) {
#pragma unroll 8
        for (int t = 0; t < CLEN; ++t) {
            int slot = t & (PF - 1);
            float delta = b2f(dpf[slot]);
            float du    = delta * b2f(upf[slot]);
            int tn = t + PF; tn = tn < CLEN ? tn : CLEN - 1;
            size_t mn = mbase + tn;
            dpf[slot] = delta16[mn * DINNER + d];
            upf[slot] = u16[mn * DINNER + d];
            float Bv[DSTATE];
            *(float4*)&Bv[0]  = *(const float4*)&lds_b[t][0];
            *(float4*)&Bv[4]  = *(const float4*)&lds_b[t][4];
            *(float4*)&Bv[8]  = *(const float4*)&lds_b[t][8];
            *(float4*)&Bv[12] = *(const float4*)&lds_b[t][12];
            float q = __builtin_amdgcn_exp2f(delta * ae[0]);
            float w = 1.f;
            sdelta += delta;
#pragma unroll
            for (int n = 0; n < DSTATE; ++n) {
                w *= q;
                h[n] = fmaf(w, h[n], du * Bv[n]);
            }
        }
    } else {
#pragma unroll 8
        for (int t = 0; t < CLEN; ++t) {
            int slot = t & (PF - 1);
            float delta = b2f(dpf[slot]);
            float du    = delta * b2f(upf[slot]);
            int tn = t + PF; tn = tn < CLEN ? tn : CLEN - 1;
            size_t mn = mbase + tn;
            dpf[slot] = delta16[mn * DINNER + d];
            upf[slot] = u16[mn * DINNER + d];
            float Bv[DSTATE];
            *(float4*)&Bv[0]  = *(const float4*)&lds_b[t][0];
            *(float4*)&Bv[4]  = *(const float4*)&lds_b[t][4];
            *(float4*)&Bv[8]  = *(const float4*)&lds_b[t][8];
            *(float4*)&Bv[12] = *(const float4*)&lds_b[t][12];
            sdelta += delta;
#pragma unroll
            for (int n = 0; n < DSTATE; ++n) {
                float w = __builtin_amdgcn_exp2f(delta * ae[n]);
                h[n] = fmaf(w, h[n], du * Bv[n]);
            }
        }
    }

    float P[DSTATE];
#pragma unroll
    for (int n = 0; n < DSTATE; ++n)
        P[n] = __builtin_amdgcn_exp2f(ae[n] * sdelta);
    float* Pp = Pws + (((size_t)c * BATCH + b) * DINNER + d) * DSTATE;
    float* Qp = Qws + (((size_t)c * BATCH + b) * DINNER + d) * DSTATE;
#pragma unroll
    for (int n = 0; n < DSTATE; n += 4) {
        *(float4*)(Pp + n) = *(float4*)&P[n];
        *(float4*)(Qp + n) = *(float4*)&h[n];
    }
}

// in-place: H0 for chunk c overwrites Pws[c]
__global__ __launch_bounds__(256) void scan_combine_kernel(
    float* __restrict__ Pws, const float* __restrict__ Qws)
{
    size_t i = (size_t)blockIdx.x * 256 + threadIdx.x;  // BATCH*DINNER*DSTATE
    const size_t stride = (size_t)BATCH * DINNER * DSTATE;
    float h = 0.f;
#pragma unroll
    for (int c = 0; c < NCHUNK; ++c) {
        float P = Pws[c * stride + i];
        float Q = Qws[c * stride + i];
        Pws[c * stride + i] = h;        // chunk-c initial state
        h = fmaf(P, h, Q);
    }
}

__global__ __launch_bounds__(256) void scan_part3_kernel(
    const uint16_t* __restrict__ delta16, const uint16_t* __restrict__ u16,
    const float* __restrict__ xdbl, const uint16_t* __restrict__ z16,
    const float* __restrict__ A_log, const float* __restrict__ Dvec,
    const float* __restrict__ H0ws, uint16_t* __restrict__ y16)
{
    __shared__ float lds_bc[CLEN][32];
    int tid = threadIdx.x;
    int d = blockIdx.x * 256 + tid;
    int b = blockIdx.y, c = blockIdx.z;
    size_t mbase = (size_t)b * T_LEN + (size_t)c * CLEN;

    {
        int r = tid >> 1, half = tid & 1;
        const float4* src = (const float4*)(xdbl + (mbase + r) * 96 + 64 + half * 16);
        float4* dst = (float4*)&lds_bc[r][half * 16];
        dst[0] = src[0]; dst[1] = src[1]; dst[2] = src[2]; dst[3] = src[3];
    }

    float ae[DSTATE];
#pragma unroll
    for (int n = 0; n < DSTATE; ++n)
        ae[n] = -__expf(A_log[d * DSTATE + n]) * LOG2E;
    bool fastexp = true;
#pragma unroll
    for (int n = 1; n < DSTATE; ++n)
        fastexp = fastexp && (fabsf(ae[n] - (n + 1) * ae[0]) <= 1e-4f * fabsf(ae[n]));
    float Dd = Dvec[d];

    float h[DSTATE];
    size_t hbase = (((size_t)c * BATCH + b) * DINNER + d) * DSTATE;
#pragma unroll
    for (int n = 0; n < DSTATE; n += 4)
        *(float4*)&h[n] = *(const float4*)(H0ws + hbase + n);

    uint16_t dpf[PF], upf[PF], rpf[PF];
#pragma unroll
    for (int t = 0; t < PF; ++t) {
        size_t m = mbase + t;
        dpf[t] = delta16[m * DINNER + d];
        upf[t] = u16[m * DINNER + d];
        rpf[t] = z16[m * 4096 + DINNER + d];
    }
    __syncthreads();

    if (fastexp) {
#pragma unroll 8
        for (int t = 0; t < CLEN; ++t) {
            int slot = t & (PF - 1);
            float delta = b2f(dpf[slot]);
            float uu    = b2f(upf[slot]);
            float rg    = b2f(rpf[slot]);
            int tn = t + PF; tn = tn < CLEN ? tn : CLEN - 1;
            size_t mn = mbase + tn;
            dpf[slot] = delta16[mn * DINNER + d];
            upf[slot] = u16[mn * DINNER + d];
            rpf[slot] = z16[mn * 4096 + DINNER + d];
            float du = delta * uu;
            float Bv[DSTATE], Cv[DSTATE];
            *(float4*)&Bv[0]  = *(const float4*)&lds_bc[t][0];
            *(float4*)&Bv[4]  = *(const float4*)&lds_bc[t][4];
            *(float4*)&Bv[8]  = *(const float4*)&lds_bc[t][8];
            *(float4*)&Bv[12] = *(const float4*)&lds_bc[t][12];
            *(float4*)&Cv[0]  = *(const float4*)&lds_bc[t][16];
            *(float4*)&Cv[4]  = *(const float4*)&lds_bc[t][20];
            *(float4*)&Cv[8]  = *(const float4*)&lds_bc[t][24];
            *(float4*)&Cv[12] = *(const float4*)&lds_bc[t][28];
            float q = __builtin_amdgcn_exp2f(delta * ae[0]);
            float w = 1.f, y = 0.f;
#pragma unroll
            for (int n = 0; n < DSTATE; ++n) {
                w *= q;
                h[n] = fmaf(w, h[n], du * Bv[n]);
                y = fmaf(h[n], Cv[n], y);
            }
            y = fmaf(uu, Dd, y);
            float sig = 1.f / (1.f + __expf(-rg));
            y16[(mbase + t) * DINNER + d] = f2b(y * rg * sig);
        }
    } else {
#pragma unroll 8
        for (int t = 0; t < CLEN; ++t) {
            int slot = t & (PF - 1);
            float delta = b2f(dpf[slot]);
            float uu    = b2f(upf[slot]);
            float rg    = b2f(rpf[slot]);
            int tn = t + PF; tn = tn < CLEN ? tn : CLEN - 1;
            size_t mn = mbase + tn;
            dpf[slot] = delta16[mn * DINNER + d];
            upf[slot] = u16[mn * DINNER + d];
            rpf[slot] = z16[mn * 4096 + DINNER + d];
            float du = delta * uu;
            float Bv[DSTATE], Cv[DSTATE];
            *(float4*)&Bv[0]  = *(const float4*)&lds_bc[t][0];
            *(float4*)&Bv[4]  = *(const float4*)&lds_bc[t][4];
            *(float4*)&Bv[8]  = *(const float4*)&lds_bc[t][8];
            *(float4*)&Bv[12] = *(const float4*)&lds_bc[t][12];
            *(float4*)&Cv[0]  = *(const float4*)&lds_bc[t][16];
            *(float4*)&Cv[4]  = *(const float4*)&lds_bc[t][20];
            *(float4*)&Cv[8]  = *(const float4*)&lds_bc[t][24];
            *(float4*)&Cv[12] = *(const float4*)&lds_bc[t][28];
            float y = 0.f;
#pragma unroll
            for (int n = 0; n < DSTATE; ++n) {
                float w = __builtin_amdgcn_exp2f(delta * ae[n]);
                h[n] = fmaf(w, h[n], du * Bv[n]);
                y = fmaf(h[n], Cv[n], y);
            }
            y = fmaf(uu, Dd, y);
            float sig = 1.f / (1.f + __expf(-rg));
            y16[(mbase + t) * DINNER + d] = f2b(y * rg * sig);
        }
    }
}

// ---------------------------------------------------------------------------
extern "C" void kernel_launch(void* const* d_in, const int* in_sizes, int n_in,
                              void* d_out, int out_size, void* d_ws, size_t ws_size,
                              hipStream_t stream)
{
    const float* x     = (const float*)d_in[0];
    const float* W_in  = (const float*)d_in[1];
    const float* cw    = (const float*)d_in[2];
    const float* cb    = (const float*)d_in[3];
    const float* W_x   = (const float*)d_in[4];
    const float* W_dt  = (const float*)d_in[5];
    const float* b_dt  = (const float*)d_in[6];
    const float* A_log = (const float*)d_in[7];
    const float* Dv    = (const float*)d_in[8];
    const float* W_out = (const float*)d_in[9];

    char* ws = (char*)d_ws;
    size_t off = 0;
    uint16_t* xb16    = (uint16_t*)(ws + off); off += (size_t)MROWS * DMODEL * 2;   // 16.8 MB
    uint16_t* WinT    = (uint16_t*)(ws + off); off += (size_t)4096 * 1024 * 2;      //  8.4 MB
    uint16_t* WoutT   = (uint16_t*)(ws + off); off += (size_t)1024 * 2048 * 2;      //  4.2 MB
    uint16_t* WxT     = (uint16_t*)(ws + off); off += (size_t)128 * 2048 * 2;       //  0.5 MB
    uint16_t* WdtT    = (uint16_t*)(ws + off); off += (size_t)2048 * 64 * 2;        //  0.26 MB
    uint16_t* z16     = (uint16_t*)(ws + off); off += (size_t)MROWS * 4096 * 2;     // 67 MB (u_raw | res)
    uint16_t* u16     = (uint16_t*)(ws + off); off += (size_t)MROWS * DINNER * 2;   // 33.5 MB
    float*    xdbl    = (float*)(ws + off);    off += (size_t)MROWS * 96 * 4;       //  3.1 MB
    uint16_t* dr16    = (uint16_t*)(ws + off); off += (size_t)MROWS * 64 * 2;       //  1.0 MB
    uint16_t* delta16 = (uint16_t*)(ws + off); off += (size_t)MROWS * DINNER * 2;   // 33.5 MB
    uint16_t* y16     = (uint16_t*)(ws + off); off += (size_t)MROWS * DINNER * 2;   // 33.5 MB

    // xb16 (16.8 MB) is dead after in_proj; it hosts, in sequence:
    //   1) xpart: split-K partials of x_proj, 4 * 8192*96*4B = 12.6 MB
    //   2) Pws+Qws: 2 * 16*4*2048*16*4B = 16.8 MB (H0 in-place in Pws)
    float* xpart = (float*)xb16;
    float* Pws   = (float*)xb16;
    float* Qws   = Pws + (size_t)NCHUNK * BATCH * DINNER * DSTATE;

    dim3 tb(32, 8);
    convert_x_kernel<<<MROWS, 256, 0, stream>>>(x, xb16);
    transpose_cvt_kernel<<<dim3(32, 128), tb, 0, stream>>>(W_in,  WinT,  1024, 4096, 4096);
    transpose_cvt_kernel<<<dim3(64, 32),  tb, 0, stream>>>(W_out, WoutT, 2048, 1024, 1024);
    transpose_cvt_kernel<<<dim3(64, 4),   tb, 0, stream>>>(W_x,   WxT,   2048, 96, 128);
    transpose_cvt_kernel<<<dim3(2, 64),   tb, 0, stream>>>(W_dt,  WdtT,  64, 2048, 2048);

    // z = X @ W_in   (8192 x 4096 x 1024)
    gemm_bt_kernel<EPI_BF16, false><<<dim3(64, 32), 256, 0, stream>>>(
        xb16, WinT, z16, nullptr, 4096, 1024, 4096, 0);
    // u = silu(causal depthwise conv(z_u) + cb)   [register sliding window]
    conv_silu_kernel<<<MROWS / CROWS, 256, 0, stream>>>(z16, cw, cb, u16);
    // x_dbl partials = u @ W_x   (8192 x 96 x 2048), split-K x4
    gemm_bt_kernel<EPI_F32G, true><<<dim3(64, 1, 4), 256, 0, stream>>>(
        u16, WxT, xpart, nullptr, 96, 2048, 96, 512);
    // reduce partials -> xdbl fp32 + dr16 bf16
    reduce_xdbl_kernel<<<MROWS, 128, 0, stream>>>(xpart, xdbl, dr16);
    // delta = softplus(delta_raw @ W_dt + b_dt)   (8192 x 2048 x 64)
    gemm_bt_kernel<EPI_SP, false><<<dim3(64, 16), 256, 0, stream>>>(
        dr16, WdtT, delta16, b_dt, 2048, 64, 2048, 0);

    // chunked selective scan, register-resident states, PF-deep prefetch
    scan_part1_kernel<<<dim3(DINNER / 256, BATCH, NCHUNK), 256, 0, stream>>>(
        delta16, u16, xdbl, A_log, Pws, Qws);
    scan_combine_kernel<<<BATCH * DINNER * DSTATE / 256, 256, 0, stream>>>(
        Pws, Qws);
    scan_part3_kernel<<<dim3(DINNER / 256, BATCH, NCHUNK), 256, 0, stream>>>(
        delta16, u16, xdbl, z16, A_log, Dv, Pws, y16);

    // out = y @ W_out   (8192 x 1024 x 2048), remapped to (t,b,c) fp32
    gemm_bt_kernel<EPI_REMAP, false><<<dim3(64, 8), 256, 0, stream>>>(
        y16, WoutT, d_out, nullptr, 1024, 2048, 1024, 0);
}

// Round 8
// 391.833 us; speedup vs baseline: 1.4251x; 1.0634x over previous
//
#include <hip/hip_runtime.h>
#include <hip/hip_bf16.h>
#include <stdint.h>

#define T_LEN   2048
#define BATCH   4
#define DMODEL  1024
#define DINNER  2048
#define DSTATE  16
#define DTRANK  64
#define MROWS   (BATCH*T_LEN)   // 8192
#define NCHUNK  32
#define CLEN    (T_LEN / NCHUNK)  // 64
#define PF      8                 // scan prefetch depth

typedef __bf16 bf16x8_t __attribute__((ext_vector_type(8)));
typedef float  f32x4_t  __attribute__((ext_vector_type(4)));

__device__ __forceinline__ uint16_t f2b(float f) {
    uint32_t u = __float_as_uint(f);
    u += 0x7fffu + ((u >> 16) & 1u);          // round-to-nearest-even
    return (uint16_t)(u >> 16);
}
__device__ __forceinline__ float b2f(uint16_t h) {
    return __uint_as_float(((uint32_t)h) << 16);
}

// async global->LDS, 16B per lane (m97 recipe)
__device__ __forceinline__ void gload16(const void* g, void* l) {
    __builtin_amdgcn_global_load_lds(
        (const __attribute__((address_space(1))) void*)g,
        (__attribute__((address_space(3))) void*)l, 16, 0, 0);
}

// ---------------------------------------------------------------------------
// x (t,b,c) fp32  ->  xb16 (b*T+t, c) bf16   (permute + convert)
// ---------------------------------------------------------------------------
__global__ __launch_bounds__(256) void convert_x_kernel(
    const float* __restrict__ x, uint16_t* __restrict__ xb)
{
    int tb = blockIdx.x;            // 0..8191, = t*4 + b
    int t = tb >> 2, b = tb & 3;
    int c = threadIdx.x * 4;
    const float4 v = *(const float4*)(x + ((size_t)tb) * DMODEL + c);
    uint16_t* dst = xb + ((size_t)(b * T_LEN + t)) * DMODEL + c;
    uint2 p;
    p.x = (uint32_t)f2b(v.x) | ((uint32_t)f2b(v.y) << 16);
    p.y = (uint32_t)f2b(v.z) | ((uint32_t)f2b(v.w) << 16);
    *(uint2*)dst = p;
}

// ---------------------------------------------------------------------------
// fused 4-matrix transpose+convert: fp32 [R][C] -> bf16 [Cpad][R]
// flattened 1D grid; per-matrix tile ranges decoded from blockIdx.x
// ---------------------------------------------------------------------------
__global__ __launch_bounds__(256) void transpose4_kernel(
    const float* __restrict__ W_in,  const float* __restrict__ W_out,
    const float* __restrict__ W_x,   const float* __restrict__ W_dt,
    uint16_t* __restrict__ WinT, uint16_t* __restrict__ WoutT,
    uint16_t* __restrict__ WxT,  uint16_t* __restrict__ WdtT)
{
    __shared__ float tile[32][33];
    int blk = blockIdx.x;
    const float* src; uint16_t* dst; int R, C, Cpad, gx;
    if (blk < 4096)      { src=W_in;  dst=WinT;  R=1024; C=4096; Cpad=4096; gx=32;  }
    else if (blk < 6144) { src=W_out; dst=WoutT; R=2048; C=1024; Cpad=1024; gx=64;  blk -= 4096; }
    else if (blk < 6400) { src=W_x;   dst=WxT;   R=2048; C=96;   Cpad=128;  gx=64;  blk -= 6144; }
    else                 { src=W_dt;  dst=WdtT;  R=64;   C=2048; Cpad=2048; gx=2;   blk -= 6400; }
    int r0 = (blk % gx) * 32;
    int c0 = (blk / gx) * 32;
    int tx = threadIdx.x & 31, ty = threadIdx.x >> 5;
#pragma unroll
    for (int i = 0; i < 32; i += 8) {
        int r = r0 + ty + i, c = c0 + tx;
        tile[ty + i][tx] = (r < R && c < C) ? src[(size_t)r * C + c] : 0.f;
    }
    __syncthreads();
#pragma unroll
    for (int i = 0; i < 32; i += 8) {
        int dr = c0 + ty + i;   // dst row = src col
        int dc = r0 + tx;       // dst col = src row
        if (dr < Cpad && dc < R) dst[(size_t)dr * R + dc] = f2b(tile[tx][ty + i]);
    }
}

// ---------------------------------------------------------------------------
// Generic bf16 MFMA GEMM: C[M][N] = A[M][K] * Bt[N][K]^T
// BK=64 K-loop (half the barrier drains of BK=32), global_load_lds width-16.
// LDS layout [128 rows][64 k] with row-XOR chunk swizzle:
//   physical 16B-chunk p at row r holds logical chunk p^(r&7); staging lane
//   tid fetches row tid>>3, logical chunk (tid&7)^((tid>>3)&7) (global reads
//   stay 128B-contiguous per 8 lanes); fragment reads hit <=2 lanes/bank.
// K must be a multiple of 64.
// ---------------------------------------------------------------------------
#define EPI_BF16  0
#define EPI_F32G  1
#define EPI_SP    2
#define EPI_REMAP 3

template <int EPI, bool SPLITK>
__global__ __launch_bounds__(256) void gemm_bt_kernel(
    const uint16_t* __restrict__ A, const uint16_t* __restrict__ Bt,
    void* __restrict__ CoutBase, const float* __restrict__ bias,
    int N, int K, int ldc, int ksplit)
{
    __shared__ uint16_t As[128 * 64];
    __shared__ uint16_t Bs[128 * 64];

    int tid = threadIdx.x;
    int bm = blockIdx.x * 128, bn = blockIdx.y * 128;
    int kbeg = SPLITK ? blockIdx.z * ksplit : 0;
    int kend = SPLITK ? kbeg + ksplit : K;
    void* Cout = SPLITK
        ? (void*)((float*)CoutBase + (size_t)blockIdx.z * MROWS * ldc)
        : CoutBase;

    int srow = tid >> 3;                          // 0..31
    int slc  = (tid & 7) ^ (srow & 7);            // logical chunk (swizzled)
    const uint16_t* ap = A  + (size_t)(bm + srow) * K + kbeg + slc * 8;
    const uint16_t* bp = Bt + (size_t)(bn + srow) * K + kbeg + slc * 8;

    f32x4_t acc[4][4];
#pragma unroll
    for (int i = 0; i < 4; i++)
#pragma unroll
        for (int j = 0; j < 4; j++) acc[i][j] = (f32x4_t){0.f, 0.f, 0.f, 0.f};

    int wid = tid >> 6, lane = tid & 63;
    int wm = (wid & 1) * 64, wn = (wid >> 1) * 64;
    int lr = lane & 15, lq = lane >> 4;
    int pc0 = (lq ^ (lr & 7)) * 8;                // phys chunk, k-step 0
    int pc1 = ((lq ^ 4) ^ (lr & 7)) * 8;          // phys chunk, k-step 1
    const uint16_t* AfS0 = &As[(wm + lr) * 64 + pc0];
    const uint16_t* AfS1 = &As[(wm + lr) * 64 + pc1];
    const uint16_t* BfS0 = &Bs[(wn + lr) * 64 + pc0];
    const uint16_t* BfS1 = &Bs[(wn + lr) * 64 + pc1];

    for (int k0 = kbeg; k0 < kend; k0 += 64) {
        __syncthreads();                       // LDS safe to overwrite
#pragma unroll
        for (int p = 0; p < 4; p++) {
            gload16(ap + (size_t)p * 32 * K, &As[(size_t)(p * 256 + tid) * 8]);
            gload16(bp + (size_t)p * 32 * K, &Bs[(size_t)(p * 256 + tid) * 8]);
        }
        ap += 64; bp += 64;
        __syncthreads();                       // drains vmcnt (async LDS stores)

        bf16x8_t av[4], bv[4];
#pragma unroll
        for (int i = 0; i < 4; i++) av[i] = *(const bf16x8_t*)(AfS0 + i * 1024);
#pragma unroll
        for (int j = 0; j < 4; j++) bv[j] = *(const bf16x8_t*)(BfS0 + j * 1024);
#pragma unroll
        for (int i = 0; i < 4; i++)
#pragma unroll
            for (int j = 0; j < 4; j++)
                acc[i][j] = __builtin_amdgcn_mfma_f32_16x16x32_bf16(
                    av[i], bv[j], acc[i][j], 0, 0, 0);
#pragma unroll
        for (int i = 0; i < 4; i++) av[i] = *(const bf16x8_t*)(AfS1 + i * 1024);
#pragma unroll
        for (int j = 0; j < 4; j++) bv[j] = *(const bf16x8_t*)(BfS1 + j * 1024);
#pragma unroll
        for (int i = 0; i < 4; i++)
#pragma unroll
            for (int j = 0; j < 4; j++)
                acc[i][j] = __builtin_amdgcn_mfma_f32_16x16x32_bf16(
                    av[i], bv[j], acc[i][j], 0, 0, 0);
    }

#pragma unroll
    for (int i = 0; i < 4; i++) {
#pragma unroll
        for (int j = 0; j < 4; j++) {
            int col = bn + wn + j * 16 + lr;
#pragma unroll
            for (int r = 0; r < 4; r++) {
                int row = bm + wm + i * 16 + lq * 4 + r;
                float v = acc[i][j][r];
                if (EPI == EPI_BF16) {
                    ((uint16_t*)Cout)[(size_t)row * ldc + col] = f2b(v);
                } else if (EPI == EPI_F32G) {
                    if (col < N) ((float*)Cout)[(size_t)row * ldc + col] = v;
                } else if (EPI == EPI_SP) {
                    float xv = v + bias[col];
                    float sp = (xv > 15.f) ? xv : __logf(1.f + __expf(xv));
                    ((uint16_t*)Cout)[(size_t)row * ldc + col] = f2b(sp);
                } else {
                    int bb = row >> 11, tt = row & (T_LEN - 1);
                    ((float*)Cout)[((size_t)(tt * BATCH + bb)) * ldc + col] = v;
                }
            }
        }
    }
}

// ---------------------------------------------------------------------------
// depthwise causal conv (width 4) + bias + SiLU — register sliding window.
// ---------------------------------------------------------------------------
#define CROWS 16

__global__ __launch_bounds__(256) void conv_silu_kernel(
    const uint16_t* __restrict__ z, const float* __restrict__ cw,
    const float* __restrict__ cb, uint16_t* __restrict__ u)
{
    int c0 = threadIdx.x * 8;           // 0..2040
    int m0 = blockIdx.x * CROWS;

    float w[8][4], bias[8];
#pragma unroll
    for (int c = 0; c < 8; ++c)
        *(float4*)w[c] = *(const float4*)(cw + (size_t)(c0 + c) * 4);
    *(float4*)&bias[0] = *(const float4*)(cb + c0);
    *(float4*)&bias[4] = *(const float4*)(cb + c0 + 4);

    float fw[4][8];
    bool seqstart = (m0 & (T_LEN - 1)) == 0;
#pragma unroll
    for (int j = 0; j < 3; ++j) {
        int m = m0 - 3 + j;
        if (seqstart) {
#pragma unroll
            for (int c = 0; c < 8; ++c) fw[j + 1][c] = 0.f;
        } else {
            uint4 v = *(const uint4*)(z + (size_t)m * 4096 + c0);
            fw[j + 1][0] = b2f((uint16_t)(v.x & 0xffff)); fw[j + 1][1] = b2f((uint16_t)(v.x >> 16));
            fw[j + 1][2] = b2f((uint16_t)(v.y & 0xffff)); fw[j + 1][3] = b2f((uint16_t)(v.y >> 16));
            fw[j + 1][4] = b2f((uint16_t)(v.z & 0xffff)); fw[j + 1][5] = b2f((uint16_t)(v.z >> 16));
            fw[j + 1][6] = b2f((uint16_t)(v.w & 0xffff)); fw[j + 1][7] = b2f((uint16_t)(v.w >> 16));
        }
    }

#pragma unroll
    for (int t = 0; t < CROWS; ++t) {
        int m = m0 + t;
        int s = t & 3;
        uint4 v = *(const uint4*)(z + (size_t)m * 4096 + c0);
        fw[s][0] = b2f((uint16_t)(v.x & 0xffff)); fw[s][1] = b2f((uint16_t)(v.x >> 16));
        fw[s][2] = b2f((uint16_t)(v.y & 0xffff)); fw[s][3] = b2f((uint16_t)(v.y >> 16));
        fw[s][4] = b2f((uint16_t)(v.z & 0xffff)); fw[s][5] = b2f((uint16_t)(v.z >> 16));
        fw[s][6] = b2f((uint16_t)(v.w & 0xffff)); fw[s][7] = b2f((uint16_t)(v.w >> 16));
        uint16_t out[8];
#pragma unroll
        for (int c = 0; c < 8; ++c) {
            float a = bias[c];
#pragma unroll
            for (int j = 0; j < 4; ++j)
                a = fmaf(fw[(t + 1 + j) & 3][c], w[c][j], a);
            float sv = a / (1.f + __expf(-a));
            out[c] = f2b(sv);
        }
        uint4 o;
        o.x = (uint32_t)out[0] | ((uint32_t)out[1] << 16);
        o.y = (uint32_t)out[2] | ((uint32_t)out[3] << 16);
        o.z = (uint32_t)out[4] | ((uint32_t)out[5] << 16);
        o.w = (uint32_t)out[6] | ((uint32_t)out[7] << 16);
        *(uint4*)(u + (size_t)m * DINNER + c0) = o;
    }
}

// ---------------------------------------------------------------------------
// reduce split-K partials of x_proj: xdbl = sum_z xpart[z], dr16 = bf16(cols<64)
// ---------------------------------------------------------------------------
__global__ __launch_bounds__(128) void reduce_xdbl_kernel(
    const float* __restrict__ xpart, float* __restrict__ xdbl,
    uint16_t* __restrict__ dr16)
{
    int m = blockIdx.x, r = threadIdx.x;
    if (r >= 96) return;
    const size_t stride = (size_t)MROWS * 96;
    size_t idx = (size_t)m * 96 + r;
    float s = xpart[idx] + xpart[stride + idx]
            + xpart[2 * stride + idx] + xpart[3 * stride + idx];
    xdbl[idx] = s;
    if (r < DTRANK) dr16[(size_t)m * DTRANK + r] = f2b(s);
}

// ---------------------------------------------------------------------------
// CHUNKED SELECTIVE SCAN, thread = (b, d, chunk), 16 n-states in regs.
// NCHUNK=32 (CLEN=64): 1024 blocks/pass = 4 blocks/CU for latency hiding.
//   * delta/u/rg prefetched PF=8 deep in rotating register slots
//   * B/C rows staged in LDS once per block (uniform ds_read thereafter)
//   * P-product via exp2(ae*sum(delta)) once per chunk (any A)
//   * fast path: A[n] = -(n+1)*A[0] -> w_n = q^(n+1), behind runtime guard
// ---------------------------------------------------------------------------
#define LOG2E 1.44269504088896340736f

__global__ __launch_bounds__(256) void scan_part1_kernel(
    const uint16_t* __restrict__ delta16, const uint16_t* __restrict__ u16,
    const float* __restrict__ xdbl, const float* __restrict__ A_log,
    float* __restrict__ Pws, float* __restrict__ Qws)
{
    __shared__ float lds_b[CLEN][16];
    int tid = threadIdx.x;
    int d = blockIdx.x * 256 + tid;
    int b = blockIdx.y, c = blockIdx.z;
    size_t mbase = (size_t)b * T_LEN + (size_t)c * CLEN;

    {   // stage B rows (xdbl cols 64..79): 64 rows x 16 floats
        int r = tid >> 2, q = tid & 3;
        *(float4*)&lds_b[r][q * 4] =
            *(const float4*)(xdbl + (mbase + r) * 96 + 64 + q * 4);
    }

    float ae[DSTATE];
#pragma unroll
    for (int n = 0; n < DSTATE; ++n)
        ae[n] = -__expf(A_log[d * DSTATE + n]) * LOG2E;
    bool fastexp = true;
#pragma unroll
    for (int n = 1; n < DSTATE; ++n)
        fastexp = fastexp && (fabsf(ae[n] - (n + 1) * ae[0]) <= 1e-4f * fabsf(ae[n]));

    float h[DSTATE];
#pragma unroll
    for (int n = 0; n < DSTATE; ++n) h[n] = 0.f;
    float sdelta = 0.f;

    uint16_t dpf[PF], upf[PF];
#pragma unroll
    for (int t = 0; t < PF; ++t) {
        size_t m = mbase + t;
        dpf[t] = delta16[m * DINNER + d];
        upf[t] = u16[m * DINNER + d];
    }
    __syncthreads();

    if (fastexp) {
#pragma unroll 8
        for (int t = 0; t < CLEN; ++t) {
            int slot = t & (PF - 1);
            float delta = b2f(dpf[slot]);
            float du    = delta * b2f(upf[slot]);
            int tn = t + PF; tn = tn < CLEN ? tn : CLEN - 1;
            size_t mn = mbase + tn;
            dpf[slot] = delta16[mn * DINNER + d];
            upf[slot] = u16[mn * DINNER + d];
            float Bv[DSTATE];
            *(float4*)&Bv[0]  = *(const float4*)&lds_b[t][0];
            *(float4*)&Bv[4]  = *(const float4*)&lds_b[t][4];
            *(float4*)&Bv[8]  = *(const float4*)&lds_b[t][8];
            *(float4*)&Bv[12] = *(const float4*)&lds_b[t][12];
            float q = __builtin_amdgcn_exp2f(delta * ae[0]);
            float w = 1.f;
            sdelta += delta;
#pragma unroll
            for (int n = 0; n < DSTATE; ++n) {
                w *= q;
                h[n] = fmaf(w, h[n], du * Bv[n]);
            }
        }
    } else {
#pragma unroll 8
        for (int t = 0; t < CLEN; ++t) {
            int slot = t & (PF - 1);
            float delta = b2f(dpf[slot]);
            float du    = delta * b2f(upf[slot]);
            int tn = t + PF; tn = tn < CLEN ? tn : CLEN - 1;
            size_t mn = mbase + tn;
            dpf[slot] = delta16[mn * DINNER + d];
            upf[slot] = u16[mn * DINNER + d];
            float Bv[DSTATE];
            *(float4*)&Bv[0]  = *(const float4*)&lds_b[t][0];
            *(float4*)&Bv[4]  = *(const float4*)&lds_b[t][4];
            *(float4*)&Bv[8]  = *(const float4*)&lds_b[t][8];
            *(float4*)&Bv[12] = *(const float4*)&lds_b[t][12];
            sdelta += delta;
#pragma unroll
            for (int n = 0; n < DSTATE; ++n) {
                float w = __builtin_amdgcn_exp2f(delta * ae[n]);
                h[n] = fmaf(w, h[n], du * Bv[n]);
            }
        }
    }

    float P[DSTATE];
#pragma unroll
    for (int n = 0; n < DSTATE; ++n)
        P[n] = __builtin_amdgcn_exp2f(ae[n] * sdelta);
    float* Pp = Pws + (((size_t)c * BATCH + b) * DINNER + d) * DSTATE;
    float* Qp = Qws + (((size_t)c * BATCH + b) * DINNER + d) * DSTATE;
#pragma unroll
    for (int n = 0; n < DSTATE; n += 4) {
        *(float4*)(Pp + n) = *(float4*)&P[n];
        *(float4*)(Qp + n) = *(float4*)&h[n];
    }
}

// in-place: H0 for chunk c overwrites Pws[c]
__global__ __launch_bounds__(256) void scan_combine_kernel(
    float* __restrict__ Pws, const float* __restrict__ Qws)
{
    size_t i = (size_t)blockIdx.x * 256 + threadIdx.x;  // BATCH*DINNER*DSTATE
    const size_t stride = (size_t)BATCH * DINNER * DSTATE;
    float h = 0.f;
#pragma unroll
    for (int c = 0; c < NCHUNK; ++c) {
        float P = Pws[c * stride + i];
        float Q = Qws[c * stride + i];
        Pws[c * stride + i] = h;        // chunk-c initial state
        h = fmaf(P, h, Q);
    }
}

__global__ __launch_bounds__(256) void scan_part3_kernel(
    const uint16_t* __restrict__ delta16, const uint16_t* __restrict__ u16,
    const float* __restrict__ xdbl, const uint16_t* __restrict__ z16,
    const float* __restrict__ A_log, const float* __restrict__ Dvec,
    const float* __restrict__ H0ws, uint16_t* __restrict__ y16)
{
    __shared__ float lds_bc[CLEN][32];
    int tid = threadIdx.x;
    int d = blockIdx.x * 256 + tid;
    int b = blockIdx.y, c = blockIdx.z;
    size_t mbase = (size_t)b * T_LEN + (size_t)c * CLEN;

    {   // stage B+C rows (xdbl cols 64..95): 64 rows x 32 floats
        int r = tid >> 2, q = tid & 3;
        const float4* src = (const float4*)(xdbl + (mbase + r) * 96 + 64 + q * 8);
        float4* dst = (float4*)&lds_bc[r][q * 8];
        dst[0] = src[0]; dst[1] = src[1];
    }

    float ae[DSTATE];
#pragma unroll
    for (int n = 0; n < DSTATE; ++n)
        ae[n] = -__expf(A_log[d * DSTATE + n]) * LOG2E;
    bool fastexp = true;
#pragma unroll
    for (int n = 1; n < DSTATE; ++n)
        fastexp = fastexp && (fabsf(ae[n] - (n + 1) * ae[0]) <= 1e-4f * fabsf(ae[n]));
    float Dd = Dvec[d];

    float h[DSTATE];
    size_t hbase = (((size_t)c * BATCH + b) * DINNER + d) * DSTATE;
#pragma unroll
    for (int n = 0; n < DSTATE; n += 4)
        *(float4*)&h[n] = *(const float4*)(H0ws + hbase + n);

    uint16_t dpf[PF], upf[PF], rpf[PF];
#pragma unroll
    for (int t = 0; t < PF; ++t) {
        size_t m = mbase + t;
        dpf[t] = delta16[m * DINNER + d];
        upf[t] = u16[m * DINNER + d];
        rpf[t] = z16[m * 4096 + DINNER + d];
    }
    __syncthreads();

    if (fastexp) {
#pragma unroll 8
        for (int t = 0; t < CLEN; ++t) {
            int slot = t & (PF - 1);
            float delta = b2f(dpf[slot]);
            float uu    = b2f(upf[slot]);
            float rg    = b2f(rpf[slot]);
            int tn = t + PF; tn = tn < CLEN ? tn : CLEN - 1;
            size_t mn = mbase + tn;
            dpf[slot] = delta16[mn * DINNER + d];
            upf[slot] = u16[mn * DINNER + d];
            rpf[slot] = z16[mn * 4096 + DINNER + d];
            float du = delta * uu;
            float Bv[DSTATE], Cv[DSTATE];
            *(float4*)&Bv[0]  = *(const float4*)&lds_bc[t][0];
            *(float4*)&Bv[4]  = *(const float4*)&lds_bc[t][4];
            *(float4*)&Bv[8]  = *(const float4*)&lds_bc[t][8];
            *(float4*)&Bv[12] = *(const float4*)&lds_bc[t][12];
            *(float4*)&Cv[0]  = *(const float4*)&lds_bc[t][16];
            *(float4*)&Cv[4]  = *(const float4*)&lds_bc[t][20];
            *(float4*)&Cv[8]  = *(const float4*)&lds_bc[t][24];
            *(float4*)&Cv[12] = *(const float4*)&lds_bc[t][28];
            float q = __builtin_amdgcn_exp2f(delta * ae[0]);
            float w = 1.f, y = 0.f;
#pragma unroll
            for (int n = 0; n < DSTATE; ++n) {
                w *= q;
                h[n] = fmaf(w, h[n], du * Bv[n]);
                y = fmaf(h[n], Cv[n], y);
            }
            y = fmaf(uu, Dd, y);
            float sig = 1.f / (1.f + __expf(-rg));
            y16[(mbase + t) * DINNER + d] = f2b(y * rg * sig);
        }
    } else {
#pragma unroll 8
        for (int t = 0; t < CLEN; ++t) {
            int slot = t & (PF - 1);
            float delta = b2f(dpf[slot]);
            float uu    = b2f(upf[slot]);
            float rg    = b2f(rpf[slot]);
            int tn = t + PF; tn = tn < CLEN ? tn : CLEN - 1;
            size_t mn = mbase + tn;
            dpf[slot] = delta16[mn * DINNER + d];
            upf[slot] = u16[mn * DINNER + d];
            rpf[slot] = z16[mn * 4096 + DINNER + d];
            float du = delta * uu;
            float Bv[DSTATE], Cv[DSTATE];
            *(float4*)&Bv[0]  = *(const float4*)&lds_bc[t][0];
            *(float4*)&Bv[4]  = *(const float4*)&lds_bc[t][4];
            *(float4*)&Bv[8]  = *(const float4*)&lds_bc[t][8];
            *(float4*)&Bv[12] = *(const float4*)&lds_bc[t][12];
            *(float4*)&Cv[0]  = *(const float4*)&lds_bc[t][16];
            *(float4*)&Cv[4]  = *(const float4*)&lds_bc[t][20];
            *(float4*)&Cv[8]  = *(const float4*)&lds_bc[t][24];
            *(float4*)&Cv[12] = *(const float4*)&lds_bc[t][28];
            float y = 0.f;
#pragma unroll
            for (int n = 0; n < DSTATE; ++n) {
                float w = __builtin_amdgcn_exp2f(delta * ae[n]);
                h[n] = fmaf(w, h[n], du * Bv[n]);
                y = fmaf(h[n], Cv[n], y);
            }
            y = fmaf(uu, Dd, y);
            float sig = 1.f / (1.f + __expf(-rg));
            y16[(mbase + t) * DINNER + d] = f2b(y * rg * sig);
        }
    }
}

// ---------------------------------------------------------------------------
extern "C" void kernel_launch(void* const* d_in, const int* in_sizes, int n_in,
                              void* d_out, int out_size, void* d_ws, size_t ws_size,
                              hipStream_t stream)
{
    const float* x     = (const float*)d_in[0];
    const float* W_in  = (const float*)d_in[1];
    const float* cw    = (const float*)d_in[2];
    const float* cb    = (const float*)d_in[3];
    const float* W_x   = (const float*)d_in[4];
    const float* W_dt  = (const float*)d_in[5];
    const float* b_dt  = (const float*)d_in[6];
    const float* A_log = (const float*)d_in[7];
    const float* Dv    = (const float*)d_in[8];
    const float* W_out = (const float*)d_in[9];

    char* ws = (char*)d_ws;
    size_t off = 0;
    uint16_t* xb16    = (uint16_t*)(ws + off); off += (size_t)MROWS * DMODEL * 2;   // 16.8 MB
    uint16_t* WinT    = (uint16_t*)(ws + off); off += (size_t)4096 * 1024 * 2;      //  8.4 MB
    uint16_t* WoutT   = (uint16_t*)(ws + off); off += (size_t)1024 * 2048 * 2;      //  4.2 MB
    uint16_t* WxT     = (uint16_t*)(ws + off); off += (size_t)128 * 2048 * 2;       //  0.5 MB
    uint16_t* WdtT    = (uint16_t*)(ws + off); off += (size_t)2048 * 64 * 2;        //  0.26 MB
    uint16_t* z16     = (uint16_t*)(ws + off); off += (size_t)MROWS * 4096 * 2;     // 67 MB (u_raw | res)
    uint16_t* u16     = (uint16_t*)(ws + off); off += (size_t)MROWS * DINNER * 2;   // 33.5 MB
    float*    xdbl    = (float*)(ws + off);    off += (size_t)MROWS * 96 * 4;       //  3.1 MB
    uint16_t* dr16    = (uint16_t*)(ws + off); off += (size_t)MROWS * 64 * 2;       //  1.0 MB
    uint16_t* delta16 = (uint16_t*)(ws + off); off += (size_t)MROWS * DINNER * 2;   // 33.5 MB
    uint16_t* y16     = (uint16_t*)(ws + off); off += (size_t)MROWS * DINNER * 2;   // 33.5 MB

    // xpart (split-K partials, 12.6 MB) aliases xb16 (dead after in_proj).
    // Pws+Qws (NCHUNK=32: 2 x 16.78 MB = 33.55 MB) alias d_out EXACTLY —
    // d_out is dead until the final GEMM, which overwrites every element.
    float* xpart = (float*)xb16;
    float* Pws   = (float*)d_out;
    float* Qws   = Pws + (size_t)NCHUNK * BATCH * DINNER * DSTATE;

    convert_x_kernel<<<MROWS, 256, 0, stream>>>(x, xb16);
    // fused transpose of all 4 weight matrices (4096+2048+256+128 tiles)
    transpose4_kernel<<<6528, 256, 0, stream>>>(
        W_in, W_out, W_x, W_dt, WinT, WoutT, WxT, WdtT);

    // z = X @ W_in   (8192 x 4096 x 1024)
    gemm_bt_kernel<EPI_BF16, false><<<dim3(64, 32), 256, 0, stream>>>(
        xb16, WinT, z16, nullptr, 4096, 1024, 4096, 0);
    // u = silu(causal depthwise conv(z_u) + cb)   [register sliding window]
    conv_silu_kernel<<<MROWS / CROWS, 256, 0, stream>>>(z16, cw, cb, u16);
    // x_dbl partials = u @ W_x   (8192 x 96 x 2048), split-K x4
    gemm_bt_kernel<EPI_F32G, true><<<dim3(64, 1, 4), 256, 0, stream>>>(
        u16, WxT, xpart, nullptr, 96, 2048, 96, 512);
    // reduce partials -> xdbl fp32 + dr16 bf16
    reduce_xdbl_kernel<<<MROWS, 128, 0, stream>>>(xpart, xdbl, dr16);
    // delta = softplus(delta_raw @ W_dt + b_dt)   (8192 x 2048 x 64)
    gemm_bt_kernel<EPI_SP, false><<<dim3(64, 16), 256, 0, stream>>>(
        dr16, WdtT, delta16, b_dt, 2048, 64, 2048, 0);

    // chunked selective scan, register-resident states, PF-deep prefetch
    scan_part1_kernel<<<dim3(DINNER / 256, BATCH, NCHUNK), 256, 0, stream>>>(
        delta16, u16, xdbl, A_log, Pws, Qws);
    scan_combine_kernel<<<BATCH * DINNER * DSTATE / 256, 256, 0, stream>>>(
        Pws, Qws);
    scan_part3_kernel<<<dim3(DINNER / 256, BATCH, NCHUNK), 256, 0, stream>>>(
        delta16, u16, xdbl, z16, A_log, Dv, Pws, y16);

    // out = y @ W_out   (8192 x 1024 x 2048), remapped to (t,b,c) fp32
    gemm_bt_kernel<EPI_REMAP, false><<<dim3(64, 8), 256, 0, stream>>>(
        y16, WoutT, d_out, nullptr, 1024, 2048, 1024, 0);
}